// Round 1
// 1118.432 us; speedup vs baseline: 1.0025x; 1.0025x over previous
//
#include <hip/hip_runtime.h>
#include <hip/hip_bf16.h>

typedef __hip_bfloat16 bf16;
typedef __attribute__((ext_vector_type(8))) short bfrag8;
typedef __attribute__((ext_vector_type(4))) float facc4;

#define NQ_ 100000
#define NP_ 200000
#define NE_ 500000

static __device__ __forceinline__ short f2bf_bits(float f) {
    bf16 h = __float2bfloat16(f);
    short r;
    __builtin_memcpy(&r, &h, 2);
    return r;
}

static __device__ __forceinline__ void store_val(bf16* p, float v) { *p = __float2bfloat16(v); }
static __device__ __forceinline__ void store_val(float* p, float v) { *p = v; }

// fp32 -> bf16 cast for BOTH feature tables in one launch, 4 elems/thread
__global__ void cast_all(const float* __restrict__ xq, const float* __restrict__ xp,
                         bf16* __restrict__ xqb, bf16* __restrict__ xpb) {
    int i = blockIdx.x * blockDim.x + threadIdx.x;
    const int nq4 = NQ_ * 32;
    float4 v;
    short4 o;
    if (i < nq4) {
        v = reinterpret_cast<const float4*>(xq)[i];
        o.x = f2bf_bits(v.x); o.y = f2bf_bits(v.y); o.z = f2bf_bits(v.z); o.w = f2bf_bits(v.w);
        reinterpret_cast<short4*>(xqb)[i] = o;
    } else {
        int j = i - nq4;
        if (j >= NP_ * 32) return;
        v = reinterpret_cast<const float4*>(xp)[j];
        o.x = f2bf_bits(v.x); o.y = f2bf_bits(v.y); o.z = f2bf_bits(v.z); o.w = f2bf_bits(v.w);
        reinterpret_cast<short4*>(xpb)[j] = o;
    }
}

// Combine + transpose weights (fp32 in, bf16 out): Wt[m][n*128+k], m = (l*2+t)*3+s
__global__ void prep_weights(const float* __restrict__ Wself, const float* __restrict__ Wneigh,
                             bf16* __restrict__ Wt) {
    int g = blockIdx.x * blockDim.x + threadIdx.x;
    if (g >= 12 * 16384) return;
    int m = g >> 14;
    int rem = g & 16383;
    int n = rem >> 7, k = rem & 127;
    int l = m / 6, t = (m / 3) % 2, s = m % 3;
    int rA = (t == 0) ? 0 : 1;
    int rB = (t == 0) ? 3 : 2;
    float v;
    if (s == 0) {
        v = Wself[((size_t)(l * 4 + rA) * 128 + k) * 128 + n]
          + Wself[((size_t)(l * 4 + rB) * 128 + k) * 128 + n];
    } else {
        int r = (s == 1) ? rA : rB;
        v = Wneigh[((size_t)(l * 4 + r) * 128 + k) * 128 + n];
    }
    Wt[(size_t)m * 16384 + n * 128 + k] = __float2bfloat16(v);
}

__global__ void prep_bias(const float* __restrict__ bias, float* __restrict__ bsum) {
    int g = blockIdx.x * blockDim.x + threadIdx.x;
    if (g >= 512) return;
    int l = g >> 8, t = (g >> 7) & 1, n = g & 127;
    int rA = (t == 0) ? 0 : 1;
    int rB = (t == 0) ? 3 : 2;
    bsum[g] = bias[(l * 4 + rA) * 128 + n] + bias[(l * 4 + rB) * 128 + n];
}

// ---------------- concatenated CSR build for all 4 relations ----------------
// dst-node space layout: [click dst: 0..NP) [qres dst: NP..2NP) [rclick dst: 2NP..2NP+NQ) [rqres: ..+NQ)

__global__ void deg_count_all(const int* __restrict__ cdst, const int* __restrict__ qdst,
                              const int* __restrict__ rcdst, const int* __restrict__ rqdst,
                              int* __restrict__ degAll) {
    int e = blockIdx.x * blockDim.x + threadIdx.x;
    if (e >= 4 * NE_) return;
    int rel = e / NE_;
    int er = e - rel * NE_;
    int d, base;
    if (rel == 0)      { d = cdst[er];  base = 0; }
    else if (rel == 1) { d = qdst[er];  base = NP_; }
    else if (rel == 2) { d = rcdst[er]; base = 2 * NP_; }
    else               { d = rqdst[er]; base = 2 * NP_ + NQ_; }
    atomicAdd(degAll + base + d, 1);
}

// pass1: per-block (1024 elems) exclusive scan -> offs, block total -> partials
__global__ void scan1(const int* __restrict__ deg, int* __restrict__ offs,
                      int* __restrict__ partials, int n) {
    __shared__ int sdata[256];
    int base = blockIdx.x * 1024;
    int t = threadIdx.x;
    int v[4]; int s = 0;
    for (int j = 0; j < 4; ++j) {
        int i = base + t * 4 + j;
        v[j] = (i < n) ? deg[i] : 0;
        s += v[j];
    }
    sdata[t] = s;
    __syncthreads();
    for (int d2 = 1; d2 < 256; d2 <<= 1) {
        int x = (t >= d2) ? sdata[t - d2] : 0;
        __syncthreads();
        sdata[t] += x;
        __syncthreads();
    }
    int excl = sdata[t] - s;
    if (t == 255) partials[blockIdx.x] = sdata[255];
    int run = excl;
    for (int j = 0; j < 4; ++j) {
        int i = base + t * 4 + j;
        if (i < n) offs[i] = run;
        run += v[j];
    }
}

// pass2: exclusive scan of partials (single block, nparts <= 1024, 4/thread)
__global__ void scan2(int* __restrict__ partials, int nparts) {
    __shared__ int sdata[256];
    int t = threadIdx.x;
    int v[4]; int s = 0;
    for (int j = 0; j < 4; ++j) {
        int i = t * 4 + j;
        v[j] = (i < nparts) ? partials[i] : 0;
        s += v[j];
    }
    sdata[t] = s;
    __syncthreads();
    for (int d2 = 1; d2 < 256; d2 <<= 1) {
        int x = (t >= d2) ? sdata[t - d2] : 0;
        __syncthreads();
        sdata[t] += x;
        __syncthreads();
    }
    int excl = sdata[t] - s;
    int run = excl;
    for (int j = 0; j < 4; ++j) {
        int i = t * 4 + j;
        if (i < nparts) partials[i] = run;
        run += v[j];
    }
}

// pass3: add block offsets; also write the cursor copy (saves a memset + add in fill)
__global__ void scan3(int* __restrict__ offs, int* __restrict__ cur,
                      const int* __restrict__ partials, int n) {
    int i = blockIdx.x * blockDim.x + threadIdx.x;
    if (i < n) {
        int v = offs[i] + partials[i >> 10];
        offs[i] = v;
        cur[i] = v;
    }
}

// bucket[cur[g]++] = src[e]  (cur holds absolute positions)
__global__ void csr_fill_all(const int* __restrict__ csrc, const int* __restrict__ cdst,
                             const int* __restrict__ qsrc, const int* __restrict__ qdst,
                             const int* __restrict__ rcsrc, const int* __restrict__ rcdst,
                             const int* __restrict__ rqsrc, const int* __restrict__ rqdst,
                             int* __restrict__ curAll, int* __restrict__ bukAll) {
    int e = blockIdx.x * blockDim.x + threadIdx.x;
    if (e >= 4 * NE_) return;
    int rel = e / NE_;
    int er = e - rel * NE_;
    int d, s, base;
    if (rel == 0)      { d = cdst[er];  s = csrc[er];  base = 0; }
    else if (rel == 1) { d = qdst[er];  s = qsrc[er];  base = NP_; }
    else if (rel == 2) { d = rcdst[er]; s = rcsrc[er]; base = 2 * NP_; }
    else               { d = rqdst[er]; s = rqsrc[er]; base = 2 * NP_ + NQ_; }
    int pos = atomicAdd(curAll + base + d, 1);
    bukAll[pos] = s;
}

// ---------------- gather-based mean aggregation, all 4 relations in one launch ----------------
// wave w handles global dst-row w; meanAll rows laid out in the same concatenated order
__global__ void gather_all(const bf16* __restrict__ hQ, const bf16* __restrict__ hP,
                           const int* __restrict__ bukAll, const int* __restrict__ offAll,
                           const int* __restrict__ degAll, bf16* __restrict__ meanAll) {
    int w = blockIdx.x * 4 + (threadIdx.x >> 6);
    int lane = threadIdx.x & 63;
    const bf16* h = (w < 2 * NP_) ? hQ : hP;  // P-dst relations source from Q, and vice versa
    int beg = offAll[w], cnt = degAll[w];
    float a0 = 0.0f, a1 = 0.0f;
    int myidx = (lane < cnt) ? bukAll[beg + lane] : 0;
    int c64 = (cnt < 64) ? cnt : 64;
    for (int i = 0; i < c64; ++i) {
        int s_ = __shfl(myidx, i);
        __hip_bfloat162 v = reinterpret_cast<const __hip_bfloat162*>(h + (size_t)s_ * 128)[lane];
        a0 += __low2float(v);
        a1 += __high2float(v);
    }
    for (int i = 64; i < cnt; ++i) {  // rare tail
        int s_ = bukAll[beg + i];
        __hip_bfloat162 v = reinterpret_cast<const __hip_bfloat162*>(h + (size_t)s_ * 128)[lane];
        a0 += __low2float(v);
        a1 += __high2float(v);
    }
    float r = (cnt > 0) ? (1.0f / (float)cnt) : 0.0f;
    unsigned lo = (unsigned short)f2bf_bits(a0 * r);
    unsigned hi = (unsigned short)f2bf_bits(a1 * r);
    reinterpret_cast<unsigned*>(meanAll + (size_t)w * 128)[lane] = (hi << 16) | lo;
}

// ---------------- fused SAGE update (MFMA), P and Q in one launch ----------------
// out[i,:] = act( hdst[i,:]@W0 + mean1[i,:]@W1 + mean2[i,:]@W2 + bias )
// B-fragments read straight from global (L2-resident W): no lW staging -> LDS 17.4KB, 3 blocks/CU
template <typename OT>
__global__ __launch_bounds__(256, 3)
void sage_all(const bf16* __restrict__ hQin, const bf16* __restrict__ hPin,
              const bf16* __restrict__ meanAll, const bf16* __restrict__ WtL,
              const float* __restrict__ bsumL,
              OT* __restrict__ outQ, OT* __restrict__ outP,
              int do_relu, int nblkP) {
    __shared__ short lA[64 * 136];  // stride 136 shorts (272B: 16B-aligned)
    const int tid = threadIdx.x;
    const int wave = tid >> 6, lane = tid & 63;
    const int i16 = lane & 15, quad = lane >> 4;

    const bool isP = (int)blockIdx.x < nblkP;
    const int blk = isP ? blockIdx.x : blockIdx.x - nblkP;
    const int row0 = blk * 64;
    const int nrows = isP ? NP_ : NQ_;
    const bf16* hdst = isP ? hPin : hQin;
    const bf16* m1 = meanAll + (isP ? (size_t)0 : (size_t)(2 * NP_)) * 128;
    const bf16* m2 = meanAll + (isP ? (size_t)NP_ : (size_t)(2 * NP_ + NQ_)) * 128;
    const bf16* Wt3 = WtL + (size_t)(isP ? 0 : 3) * 16384;
    const float* bs = bsumL + (isP ? 0 : 128);
    OT* out = isP ? outP : outQ;

    facc4 acc[4][2];
    for (int nt = 0; nt < 2; ++nt) {
        float bv = bs[wave * 32 + nt * 16 + i16];
        for (int mt = 0; mt < 4; ++mt) {
            facc4 a = {bv, bv, bv, bv};
            acc[mt][nt] = a;
        }
    }

    const bf16* Asrc[3] = {hdst, m1, m2};
#pragma unroll
    for (int s = 0; s < 3; ++s) {
        __syncthreads();
        // stage A_s (64 x 128 bf16)
        {
            const bf16* A = Asrc[s];
            for (int j = 0; j < 4; ++j) {
                int c = j * 256 + tid;
                int r = c >> 4, k = (c & 15) * 8;
                int grow = row0 + r;
                int4 v = {0, 0, 0, 0};
                if (grow < nrows)
                    v = reinterpret_cast<const int4*>(A)[((size_t)grow * 128 + k) >> 3];
                *reinterpret_cast<int4*>(&lA[r * 136 + k]) = v;
            }
        }
        __syncthreads();
        const bf16* Ws = Wt3 + (size_t)s * 16384;
#pragma unroll
        for (int k0 = 0; k0 < 128; k0 += 32) {
            bfrag8 a[4], b[2];
            for (int mt = 0; mt < 4; ++mt)
                a[mt] = *reinterpret_cast<const bfrag8*>(&lA[(mt * 16 + i16) * 136 + k0 + quad * 8]);
            for (int nt = 0; nt < 2; ++nt)
                b[nt] = *reinterpret_cast<const bfrag8*>(
                    Ws + (size_t)(wave * 32 + nt * 16 + i16) * 128 + k0 + quad * 8);
            for (int mt = 0; mt < 4; ++mt)
                for (int nt = 0; nt < 2; ++nt)
                    acc[mt][nt] = __builtin_amdgcn_mfma_f32_16x16x32_bf16(a[mt], b[nt], acc[mt][nt], 0, 0, 0);
        }
    }

    for (int mt = 0; mt < 4; ++mt) {
        for (int nt = 0; nt < 2; ++nt) {
            int n = wave * 32 + nt * 16 + i16;
            for (int r = 0; r < 4; ++r) {
                int m = mt * 16 + quad * 4 + r;
                int grow = row0 + m;
                if (grow < nrows) {
                    float v = acc[mt][nt][r];
                    if (do_relu) v = fmaxf(v, 0.0f);
                    store_val(out + (size_t)grow * 128 + n, v);
                }
            }
        }
    }
}

// ---------------- launch ----------------

extern "C" void kernel_launch(void* const* d_in, const int* in_sizes, int n_in,
                              void* d_out, int out_size, void* d_ws, size_t ws_size,
                              hipStream_t stream) {
    const float* xq     = (const float*)d_in[0];
    const float* xp     = (const float*)d_in[1];
    const float* Wself  = (const float*)d_in[2];
    const float* Wneigh = (const float*)d_in[3];
    const float* bias   = (const float*)d_in[4];
    const int* csrc  = (const int*)d_in[5];
    const int* cdst  = (const int*)d_in[6];
    const int* qsrc  = (const int*)d_in[7];
    const int* qdst  = (const int*)d_in[8];
    const int* rcsrc = (const int*)d_in[9];
    const int* rcdst = (const int*)d_in[10];
    const int* rqsrc = (const int*)d_in[11];
    const int* rqdst = (const int*)d_in[12];

    const int NDST = 2 * NP_ + 2 * NQ_;  // 600000 concatenated dst rows

    char* w = (char*)d_ws;
    bf16* xqb    = (bf16*)w;  w += (size_t)NQ_ * 128 * 2;
    bf16* xpb    = (bf16*)w;  w += (size_t)NP_ * 128 * 2;
    bf16* hQ1    = (bf16*)w;  w += (size_t)NQ_ * 128 * 2;
    bf16* hP1    = (bf16*)w;  w += (size_t)NP_ * 128 * 2;
    bf16* meanAll = (bf16*)w; w += (size_t)NDST * 128 * 2;
    bf16* Wt     = (bf16*)w;  w += (size_t)12 * 16384 * 2;
    float* bsum  = (float*)w; w += 512 * 4;
    int* degAll  = (int*)w;   w += (size_t)NDST * 4;
    int* offAll  = (int*)w;   w += (size_t)NDST * 4;
    int* curAll  = (int*)w;   w += (size_t)NDST * 4;
    int* bukAll  = (int*)w;   w += (size_t)4 * NE_ * 4;
    int* partials = (int*)w;  w += 1024 * 4;

    float* outQ = (float*)d_out;
    float* outP = outQ + (size_t)NQ_ * 128;

    // --- one-time prep ---
    cast_all<<<((NQ_ + NP_) * 32 + 255) / 256, 256, 0, stream>>>(xq, xp, xqb, xpb);
    prep_weights<<<768, 256, 0, stream>>>(Wself, Wneigh, Wt);
    prep_bias<<<2, 256, 0, stream>>>(bias, bsum);

    // --- concatenated CSR build (one pass for all 4 relations) ---
    hipMemsetAsync(degAll, 0, (size_t)NDST * 4, stream);
    deg_count_all<<<(4 * NE_ + 255) / 256, 256, 0, stream>>>(cdst, qdst, rcdst, rqdst, degAll);
    int nparts = (NDST + 1023) / 1024;  // 586
    scan1<<<nparts, 256, 0, stream>>>(degAll, offAll, partials, NDST);
    scan2<<<1, 256, 0, stream>>>(partials, nparts);
    scan3<<<(NDST + 255) / 256, 256, 0, stream>>>(offAll, curAll, partials, NDST);
    csr_fill_all<<<(4 * NE_ + 255) / 256, 256, 0, stream>>>(csrc, cdst, qsrc, qdst,
                                                            rcsrc, rcdst, rqsrc, rqdst,
                                                            curAll, bukAll);

    const int nblkP = (NP_ + 63) / 64;            // 3125
    const int nblkQ = (NQ_ + 63) / 64;            // 1563
    const int gather_blocks = NDST / 4;           // 150000 (exact)

    for (int l = 0; l < 2; ++l) {
        const bf16* hQin = l ? hQ1 : xqb;
        const bf16* hPin = l ? hP1 : xpb;
        const bf16* WtL = Wt + (size_t)l * 6 * 16384;
        const float* bL = bsum + l * 256;

        gather_all<<<gather_blocks, 256, 0, stream>>>(hQin, hPin, bukAll, offAll, degAll, meanAll);

        if (l == 0)
            sage_all<bf16><<<nblkP + nblkQ, 256, 0, stream>>>(hQin, hPin, meanAll, WtL, bL,
                                                              hQ1, hP1, 1, nblkP);
        else
            sage_all<float><<<nblkP + nblkQ, 256, 0, stream>>>(hQin, hPin, meanAll, WtL, bL,
                                                               outQ, outP, 0, nblkP);
    }
}

// Round 2
// 900.225 us; speedup vs baseline: 1.2455x; 1.2424x over previous
//
#include <hip/hip_runtime.h>
#include <hip/hip_bf16.h>

typedef __hip_bfloat16 bf16;
typedef __attribute__((ext_vector_type(8))) short bfrag8;
typedef __attribute__((ext_vector_type(4))) float facc4;

#define NQ_ 100000
#define NP_ 200000
#define NE_ 500000

static __device__ __forceinline__ short f2bf_bits(float f) {
    bf16 h = __float2bfloat16(f);
    short r;
    __builtin_memcpy(&r, &h, 2);
    return r;
}

static __device__ __forceinline__ void store_val(bf16* p, float v) { *p = __float2bfloat16(v); }
static __device__ __forceinline__ void store_val(float* p, float v) { *p = v; }

// fp32 -> bf16 cast for BOTH feature tables in one launch, 4 elems/thread
__global__ void cast_all(const float* __restrict__ xq, const float* __restrict__ xp,
                         bf16* __restrict__ xqb, bf16* __restrict__ xpb) {
    int i = blockIdx.x * blockDim.x + threadIdx.x;
    const int nq4 = NQ_ * 32;
    float4 v;
    short4 o;
    if (i < nq4) {
        v = reinterpret_cast<const float4*>(xq)[i];
        o.x = f2bf_bits(v.x); o.y = f2bf_bits(v.y); o.z = f2bf_bits(v.z); o.w = f2bf_bits(v.w);
        reinterpret_cast<short4*>(xqb)[i] = o;
    } else {
        int j = i - nq4;
        if (j >= NP_ * 32) return;
        v = reinterpret_cast<const float4*>(xp)[j];
        o.x = f2bf_bits(v.x); o.y = f2bf_bits(v.y); o.z = f2bf_bits(v.z); o.w = f2bf_bits(v.w);
        reinterpret_cast<short4*>(xpb)[j] = o;
    }
}

// Combine + transpose weights (fp32 in, bf16 out): Wt[m][n*128+k], m = (l*2+t)*3+s
__global__ void prep_weights(const float* __restrict__ Wself, const float* __restrict__ Wneigh,
                             bf16* __restrict__ Wt) {
    int g = blockIdx.x * blockDim.x + threadIdx.x;
    if (g >= 12 * 16384) return;
    int m = g >> 14;
    int rem = g & 16383;
    int n = rem >> 7, k = rem & 127;
    int l = m / 6, t = (m / 3) % 2, s = m % 3;
    int rA = (t == 0) ? 0 : 1;
    int rB = (t == 0) ? 3 : 2;
    float v;
    if (s == 0) {
        v = Wself[((size_t)(l * 4 + rA) * 128 + k) * 128 + n]
          + Wself[((size_t)(l * 4 + rB) * 128 + k) * 128 + n];
    } else {
        int r = (s == 1) ? rA : rB;
        v = Wneigh[((size_t)(l * 4 + r) * 128 + k) * 128 + n];
    }
    Wt[(size_t)m * 16384 + n * 128 + k] = __float2bfloat16(v);
}

__global__ void prep_bias(const float* __restrict__ bias, float* __restrict__ bsum) {
    int g = blockIdx.x * blockDim.x + threadIdx.x;
    if (g >= 512) return;
    int l = g >> 8, t = (g >> 7) & 1, n = g & 127;
    int rA = (t == 0) ? 0 : 1;
    int rB = (t == 0) ? 3 : 2;
    bsum[g] = bias[(l * 4 + rA) * 128 + n] + bias[(l * 4 + rB) * 128 + n];
}

// ---------------- concatenated CSR build for all 4 relations ----------------
// dst-node space layout: [click dst: 0..NP) [qres dst: NP..2NP) [rclick dst: 2NP..2NP+NQ) [rqres: ..+NQ)

__global__ void deg_count_all(const int* __restrict__ cdst, const int* __restrict__ qdst,
                              const int* __restrict__ rcdst, const int* __restrict__ rqdst,
                              int* __restrict__ degAll) {
    int e = blockIdx.x * blockDim.x + threadIdx.x;
    if (e >= 4 * NE_) return;
    int rel = e / NE_;
    int er = e - rel * NE_;
    int d, base;
    if (rel == 0)      { d = cdst[er];  base = 0; }
    else if (rel == 1) { d = qdst[er];  base = NP_; }
    else if (rel == 2) { d = rcdst[er]; base = 2 * NP_; }
    else               { d = rqdst[er]; base = 2 * NP_ + NQ_; }
    atomicAdd(degAll + base + d, 1);
}

// pass1: per-block (1024 elems) exclusive scan -> offs, block total -> partials
__global__ void scan1(const int* __restrict__ deg, int* __restrict__ offs,
                      int* __restrict__ partials, int n) {
    __shared__ int sdata[256];
    int base = blockIdx.x * 1024;
    int t = threadIdx.x;
    int v[4]; int s = 0;
    for (int j = 0; j < 4; ++j) {
        int i = base + t * 4 + j;
        v[j] = (i < n) ? deg[i] : 0;
        s += v[j];
    }
    sdata[t] = s;
    __syncthreads();
    for (int d2 = 1; d2 < 256; d2 <<= 1) {
        int x = (t >= d2) ? sdata[t - d2] : 0;
        __syncthreads();
        sdata[t] += x;
        __syncthreads();
    }
    int excl = sdata[t] - s;
    if (t == 255) partials[blockIdx.x] = sdata[255];
    int run = excl;
    for (int j = 0; j < 4; ++j) {
        int i = base + t * 4 + j;
        if (i < n) offs[i] = run;
        run += v[j];
    }
}

// pass2: exclusive scan of partials (single block, nparts <= 1024, 4/thread)
__global__ void scan2(int* __restrict__ partials, int nparts) {
    __shared__ int sdata[256];
    int t = threadIdx.x;
    int v[4]; int s = 0;
    for (int j = 0; j < 4; ++j) {
        int i = t * 4 + j;
        v[j] = (i < nparts) ? partials[i] : 0;
        s += v[j];
    }
    sdata[t] = s;
    __syncthreads();
    for (int d2 = 1; d2 < 256; d2 <<= 1) {
        int x = (t >= d2) ? sdata[t - d2] : 0;
        __syncthreads();
        sdata[t] += x;
        __syncthreads();
    }
    int excl = sdata[t] - s;
    int run = excl;
    for (int j = 0; j < 4; ++j) {
        int i = t * 4 + j;
        if (i < nparts) partials[i] = run;
        run += v[j];
    }
}

// pass3: add block offsets; also write the cursor copy (saves a memset + add in fill)
__global__ void scan3(int* __restrict__ offs, int* __restrict__ cur,
                      const int* __restrict__ partials, int n) {
    int i = blockIdx.x * blockDim.x + threadIdx.x;
    if (i < n) {
        int v = offs[i] + partials[i >> 10];
        offs[i] = v;
        cur[i] = v;
    }
}

// bucket[cur[g]++] = src[e]  (cur holds absolute positions)
__global__ void csr_fill_all(const int* __restrict__ csrc, const int* __restrict__ cdst,
                             const int* __restrict__ qsrc, const int* __restrict__ qdst,
                             const int* __restrict__ rcsrc, const int* __restrict__ rcdst,
                             const int* __restrict__ rqsrc, const int* __restrict__ rqdst,
                             int* __restrict__ curAll, int* __restrict__ bukAll) {
    int e = blockIdx.x * blockDim.x + threadIdx.x;
    if (e >= 4 * NE_) return;
    int rel = e / NE_;
    int er = e - rel * NE_;
    int d, s, base;
    if (rel == 0)      { d = cdst[er];  s = csrc[er];  base = 0; }
    else if (rel == 1) { d = qdst[er];  s = qsrc[er];  base = NP_; }
    else if (rel == 2) { d = rcdst[er]; s = rcsrc[er]; base = 2 * NP_; }
    else               { d = rqdst[er]; s = rqsrc[er]; base = 2 * NP_ + NQ_; }
    int pos = atomicAdd(curAll + base + d, 1);
    bukAll[pos] = s;
}

// ---------------- gather-based mean aggregation, all 4 relations in one launch ----------------
// 4 dst rows per wave, 16 lanes per row, int4 (16B = 8 bf16) per lane.
// 4 independent neighbor streams per wave -> 4x memory-level parallelism vs 1-row-per-wave.
__global__ __launch_bounds__(256, 8)
void gather_all(const bf16* __restrict__ hQ, const bf16* __restrict__ hP,
                const int* __restrict__ bukAll, const int* __restrict__ offAll,
                const int* __restrict__ degAll, bf16* __restrict__ meanAll) {
    const int tid = threadIdx.x;
    const int lane = tid & 63;
    const int g = lane >> 4;       // row-group within wave (0..3)
    const int li = lane & 15;      // lane within group: handles feats 8*li..8*li+7
    const int w = blockIdx.x * 16 + (tid >> 6) * 4 + g;  // dst row; grid sized exactly
    const bf16* h = (w < 2 * NP_) ? hQ : hP;  // P-dst relations source from Q, vice versa
    const int beg = offAll[w];
    const int cnt = degAll[w];

    float a0 = 0.f, a1 = 0.f, a2 = 0.f, a3 = 0.f, a4 = 0.f, a5 = 0.f, a6 = 0.f, a7 = 0.f;

    int myidx = (li < cnt) ? bukAll[beg + li] : 0;
    int c16 = (cnt < 16) ? cnt : 16;
    for (int i = 0; i < c16; ++i) {
        int s_ = __shfl(myidx, g * 16 + i);
        int4 v = reinterpret_cast<const int4*>(h + (size_t)s_ * 128)[li];
        unsigned u0 = (unsigned)v.x, u1 = (unsigned)v.y, u2 = (unsigned)v.z, u3 = (unsigned)v.w;
        a0 += __builtin_bit_cast(float, u0 << 16);
        a1 += __builtin_bit_cast(float, u0 & 0xffff0000u);
        a2 += __builtin_bit_cast(float, u1 << 16);
        a3 += __builtin_bit_cast(float, u1 & 0xffff0000u);
        a4 += __builtin_bit_cast(float, u2 << 16);
        a5 += __builtin_bit_cast(float, u2 & 0xffff0000u);
        a6 += __builtin_bit_cast(float, u3 << 16);
        a7 += __builtin_bit_cast(float, u3 & 0xffff0000u);
    }
    for (int i = 16; i < cnt; ++i) {  // rare tail (deg > 16)
        int s_ = bukAll[beg + i];
        int4 v = reinterpret_cast<const int4*>(h + (size_t)s_ * 128)[li];
        unsigned u0 = (unsigned)v.x, u1 = (unsigned)v.y, u2 = (unsigned)v.z, u3 = (unsigned)v.w;
        a0 += __builtin_bit_cast(float, u0 << 16);
        a1 += __builtin_bit_cast(float, u0 & 0xffff0000u);
        a2 += __builtin_bit_cast(float, u1 << 16);
        a3 += __builtin_bit_cast(float, u1 & 0xffff0000u);
        a4 += __builtin_bit_cast(float, u2 << 16);
        a5 += __builtin_bit_cast(float, u2 & 0xffff0000u);
        a6 += __builtin_bit_cast(float, u3 << 16);
        a7 += __builtin_bit_cast(float, u3 & 0xffff0000u);
    }

    float r = (cnt > 0) ? (1.0f / (float)cnt) : 0.0f;
    unsigned o0 = ((unsigned)(unsigned short)f2bf_bits(a1 * r) << 16) | (unsigned short)f2bf_bits(a0 * r);
    unsigned o1 = ((unsigned)(unsigned short)f2bf_bits(a3 * r) << 16) | (unsigned short)f2bf_bits(a2 * r);
    unsigned o2 = ((unsigned)(unsigned short)f2bf_bits(a5 * r) << 16) | (unsigned short)f2bf_bits(a4 * r);
    unsigned o3 = ((unsigned)(unsigned short)f2bf_bits(a7 * r) << 16) | (unsigned short)f2bf_bits(a6 * r);
    int4 ov;
    ov.x = (int)o0; ov.y = (int)o1; ov.z = (int)o2; ov.w = (int)o3;
    reinterpret_cast<int4*>(meanAll + (size_t)w * 128)[li] = ov;
}

// ---------------- fused SAGE update (MFMA), P and Q in one launch ----------------
// out[i,:] = act( hdst[i,:]@W0 + mean1[i,:]@W1 + mean2[i,:]@W2 + bias )
// B-fragments read straight from global (L2-resident W): no lW staging -> LDS 17.4KB, 3 blocks/CU
template <typename OT>
__global__ __launch_bounds__(256, 3)
void sage_all(const bf16* __restrict__ hQin, const bf16* __restrict__ hPin,
              const bf16* __restrict__ meanAll, const bf16* __restrict__ WtL,
              const float* __restrict__ bsumL,
              OT* __restrict__ outQ, OT* __restrict__ outP,
              int do_relu, int nblkP) {
    __shared__ short lA[64 * 136];  // stride 136 shorts (272B: 16B-aligned)
    const int tid = threadIdx.x;
    const int wave = tid >> 6, lane = tid & 63;
    const int i16 = lane & 15, quad = lane >> 4;

    const bool isP = (int)blockIdx.x < nblkP;
    const int blk = isP ? blockIdx.x : blockIdx.x - nblkP;
    const int row0 = blk * 64;
    const int nrows = isP ? NP_ : NQ_;
    const bf16* hdst = isP ? hPin : hQin;
    const bf16* m1 = meanAll + (isP ? (size_t)0 : (size_t)(2 * NP_)) * 128;
    const bf16* m2 = meanAll + (isP ? (size_t)NP_ : (size_t)(2 * NP_ + NQ_)) * 128;
    const bf16* Wt3 = WtL + (size_t)(isP ? 0 : 3) * 16384;
    const float* bs = bsumL + (isP ? 0 : 128);
    OT* out = isP ? outP : outQ;

    facc4 acc[4][2];
    for (int nt = 0; nt < 2; ++nt) {
        float bv = bs[wave * 32 + nt * 16 + i16];
        for (int mt = 0; mt < 4; ++mt) {
            facc4 a = {bv, bv, bv, bv};
            acc[mt][nt] = a;
        }
    }

    const bf16* Asrc[3] = {hdst, m1, m2};
#pragma unroll
    for (int s = 0; s < 3; ++s) {
        __syncthreads();
        // stage A_s (64 x 128 bf16)
        {
            const bf16* A = Asrc[s];
            for (int j = 0; j < 4; ++j) {
                int c = j * 256 + tid;
                int r = c >> 4, k = (c & 15) * 8;
                int grow = row0 + r;
                int4 v = {0, 0, 0, 0};
                if (grow < nrows)
                    v = reinterpret_cast<const int4*>(A)[((size_t)grow * 128 + k) >> 3];
                *reinterpret_cast<int4*>(&lA[r * 136 + k]) = v;
            }
        }
        __syncthreads();
        const bf16* Ws = Wt3 + (size_t)s * 16384;
#pragma unroll
        for (int k0 = 0; k0 < 128; k0 += 32) {
            bfrag8 a[4], b[2];
            for (int mt = 0; mt < 4; ++mt)
                a[mt] = *reinterpret_cast<const bfrag8*>(&lA[(mt * 16 + i16) * 136 + k0 + quad * 8]);
            for (int nt = 0; nt < 2; ++nt)
                b[nt] = *reinterpret_cast<const bfrag8*>(
                    Ws + (size_t)(wave * 32 + nt * 16 + i16) * 128 + k0 + quad * 8);
            for (int mt = 0; mt < 4; ++mt)
                for (int nt = 0; nt < 2; ++nt)
                    acc[mt][nt] = __builtin_amdgcn_mfma_f32_16x16x32_bf16(a[mt], b[nt], acc[mt][nt], 0, 0, 0);
        }
    }

    for (int mt = 0; mt < 4; ++mt) {
        for (int nt = 0; nt < 2; ++nt) {
            int n = wave * 32 + nt * 16 + i16;
            for (int r = 0; r < 4; ++r) {
                int m = mt * 16 + quad * 4 + r;
                int grow = row0 + m;
                if (grow < nrows) {
                    float v = acc[mt][nt][r];
                    if (do_relu) v = fmaxf(v, 0.0f);
                    store_val(out + (size_t)grow * 128 + n, v);
                }
            }
        }
    }
}

// ---------------- launch ----------------

extern "C" void kernel_launch(void* const* d_in, const int* in_sizes, int n_in,
                              void* d_out, int out_size, void* d_ws, size_t ws_size,
                              hipStream_t stream) {
    const float* xq     = (const float*)d_in[0];
    const float* xp     = (const float*)d_in[1];
    const float* Wself  = (const float*)d_in[2];
    const float* Wneigh = (const float*)d_in[3];
    const float* bias   = (const float*)d_in[4];
    const int* csrc  = (const int*)d_in[5];
    const int* cdst  = (const int*)d_in[6];
    const int* qsrc  = (const int*)d_in[7];
    const int* qdst  = (const int*)d_in[8];
    const int* rcsrc = (const int*)d_in[9];
    const int* rcdst = (const int*)d_in[10];
    const int* rqsrc = (const int*)d_in[11];
    const int* rqdst = (const int*)d_in[12];

    const int NDST = 2 * NP_ + 2 * NQ_;  // 600000 concatenated dst rows

    char* w = (char*)d_ws;
    bf16* xqb    = (bf16*)w;  w += (size_t)NQ_ * 128 * 2;
    bf16* xpb    = (bf16*)w;  w += (size_t)NP_ * 128 * 2;
    bf16* hQ1    = (bf16*)w;  w += (size_t)NQ_ * 128 * 2;
    bf16* hP1    = (bf16*)w;  w += (size_t)NP_ * 128 * 2;
    bf16* meanAll = (bf16*)w; w += (size_t)NDST * 128 * 2;
    bf16* Wt     = (bf16*)w;  w += (size_t)12 * 16384 * 2;
    float* bsum  = (float*)w; w += 512 * 4;
    int* degAll  = (int*)w;   w += (size_t)NDST * 4;
    int* offAll  = (int*)w;   w += (size_t)NDST * 4;
    int* curAll  = (int*)w;   w += (size_t)NDST * 4;
    int* bukAll  = (int*)w;   w += (size_t)4 * NE_ * 4;
    int* partials = (int*)w;  w += 1024 * 4;

    float* outQ = (float*)d_out;
    float* outP = outQ + (size_t)NQ_ * 128;

    // --- one-time prep ---
    cast_all<<<((NQ_ + NP_) * 32 + 255) / 256, 256, 0, stream>>>(xq, xp, xqb, xpb);
    prep_weights<<<768, 256, 0, stream>>>(Wself, Wneigh, Wt);
    prep_bias<<<2, 256, 0, stream>>>(bias, bsum);

    // --- concatenated CSR build (one pass for all 4 relations) ---
    hipMemsetAsync(degAll, 0, (size_t)NDST * 4, stream);
    deg_count_all<<<(4 * NE_ + 255) / 256, 256, 0, stream>>>(cdst, qdst, rcdst, rqdst, degAll);
    int nparts = (NDST + 1023) / 1024;  // 586
    scan1<<<nparts, 256, 0, stream>>>(degAll, offAll, partials, NDST);
    scan2<<<1, 256, 0, stream>>>(partials, nparts);
    scan3<<<(NDST + 255) / 256, 256, 0, stream>>>(offAll, curAll, partials, NDST);
    csr_fill_all<<<(4 * NE_ + 255) / 256, 256, 0, stream>>>(csrc, cdst, qsrc, qdst,
                                                            rcsrc, rcdst, rqsrc, rqdst,
                                                            curAll, bukAll);

    const int nblkP = (NP_ + 63) / 64;            // 3125
    const int nblkQ = (NQ_ + 63) / 64;            // 1563
    const int gather_blocks = NDST / 16;          // 37500 (exact: 16 rows per block)

    for (int l = 0; l < 2; ++l) {
        const bf16* hQin = l ? hQ1 : xqb;
        const bf16* hPin = l ? hP1 : xpb;
        const bf16* WtL = Wt + (size_t)l * 6 * 16384;
        const float* bL = bsum + l * 256;

        gather_all<<<gather_blocks, 256, 0, stream>>>(hQin, hPin, bukAll, offAll, degAll, meanAll);

        if (l == 0)
            sage_all<bf16><<<nblkP + nblkQ, 256, 0, stream>>>(hQin, hPin, meanAll, WtL, bL,
                                                              hQ1, hP1, 1, nblkP);
        else
            sage_all<float><<<nblkP + nblkQ, 256, 0, stream>>>(hQin, hPin, meanAll, WtL, bL,
                                                               outQ, outP, 0, nblkP);
    }
}

// Round 3
// 897.555 us; speedup vs baseline: 1.2492x; 1.0030x over previous
//
#include <hip/hip_runtime.h>
#include <hip/hip_bf16.h>

typedef __hip_bfloat16 bf16;
typedef __attribute__((ext_vector_type(8))) short bfrag8;
typedef __attribute__((ext_vector_type(4))) float facc4;

#define NQ_ 100000
#define NP_ 200000
#define NE_ 500000

static __device__ __forceinline__ short f2bf_bits(float f) {
    bf16 h = __float2bfloat16(f);
    short r;
    __builtin_memcpy(&r, &h, 2);
    return r;
}

static __device__ __forceinline__ float bfbits2f(unsigned u) {
    return __builtin_bit_cast(float, u);
}

static __device__ __forceinline__ void store_val(bf16* p, float v) { *p = __float2bfloat16(v); }
static __device__ __forceinline__ void store_val(float* p, float v) { *p = v; }

// fp32 -> bf16 cast for BOTH feature tables in one launch, 4 elems/thread
__global__ void cast_all(const float* __restrict__ xq, const float* __restrict__ xp,
                         bf16* __restrict__ xqb, bf16* __restrict__ xpb) {
    int i = blockIdx.x * blockDim.x + threadIdx.x;
    const int nq4 = NQ_ * 32;
    float4 v;
    short4 o;
    if (i < nq4) {
        v = reinterpret_cast<const float4*>(xq)[i];
        o.x = f2bf_bits(v.x); o.y = f2bf_bits(v.y); o.z = f2bf_bits(v.z); o.w = f2bf_bits(v.w);
        reinterpret_cast<short4*>(xqb)[i] = o;
    } else {
        int j = i - nq4;
        if (j >= NP_ * 32) return;
        v = reinterpret_cast<const float4*>(xp)[j];
        o.x = f2bf_bits(v.x); o.y = f2bf_bits(v.y); o.z = f2bf_bits(v.z); o.w = f2bf_bits(v.w);
        reinterpret_cast<short4*>(xpb)[j] = o;
    }
}

// Combine + transpose weights (fp32 in, bf16 out): Wt[m][n*128+k], m = (l*2+t)*3+s
__global__ void prep_weights(const float* __restrict__ Wself, const float* __restrict__ Wneigh,
                             bf16* __restrict__ Wt) {
    int g = blockIdx.x * blockDim.x + threadIdx.x;
    if (g >= 12 * 16384) return;
    int m = g >> 14;
    int rem = g & 16383;
    int n = rem >> 7, k = rem & 127;
    int l = m / 6, t = (m / 3) % 2, s = m % 3;
    int rA = (t == 0) ? 0 : 1;
    int rB = (t == 0) ? 3 : 2;
    float v;
    if (s == 0) {
        v = Wself[((size_t)(l * 4 + rA) * 128 + k) * 128 + n]
          + Wself[((size_t)(l * 4 + rB) * 128 + k) * 128 + n];
    } else {
        int r = (s == 1) ? rA : rB;
        v = Wneigh[((size_t)(l * 4 + r) * 128 + k) * 128 + n];
    }
    Wt[(size_t)m * 16384 + n * 128 + k] = __float2bfloat16(v);
}

__global__ void prep_bias(const float* __restrict__ bias, float* __restrict__ bsum) {
    int g = blockIdx.x * blockDim.x + threadIdx.x;
    if (g >= 512) return;
    int l = g >> 8, t = (g >> 7) & 1, n = g & 127;
    int rA = (t == 0) ? 0 : 1;
    int rB = (t == 0) ? 3 : 2;
    bsum[g] = bias[(l * 4 + rA) * 128 + n] + bias[(l * 4 + rB) * 128 + n];
}

// ---------------- concatenated CSR build for all 4 relations ----------------
// dst-node space layout: [click dst: 0..NP) [qres dst: NP..2NP) [rclick dst: 2NP..2NP+NQ) [rqres: ..+NQ)
// 4 edges per thread (int4 loads) -> 4 independent atomic chains in flight per lane.

#define NE4_ (NE_ / 4)  // 125000

__global__ void deg_count_all(const int* __restrict__ cdst, const int* __restrict__ qdst,
                              const int* __restrict__ rcdst, const int* __restrict__ rqdst,
                              int* __restrict__ degAll) {
    int t = blockIdx.x * blockDim.x + threadIdx.x;
    if (t >= 4 * NE4_) return;
    int rel = t / NE4_;
    int er = (t - rel * NE4_) * 4;
    const int* dsts; int base;
    if (rel == 0)      { dsts = cdst;  base = 0; }
    else if (rel == 1) { dsts = qdst;  base = NP_; }
    else if (rel == 2) { dsts = rcdst; base = 2 * NP_; }
    else               { dsts = rqdst; base = 2 * NP_ + NQ_; }
    int4 d4 = *reinterpret_cast<const int4*>(dsts + er);
    atomicAdd(degAll + base + d4.x, 1);
    atomicAdd(degAll + base + d4.y, 1);
    atomicAdd(degAll + base + d4.z, 1);
    atomicAdd(degAll + base + d4.w, 1);
}

// pass1: per-block (1024 elems) exclusive scan -> offs, block total -> partials
__global__ void scan1(const int* __restrict__ deg, int* __restrict__ offs,
                      int* __restrict__ partials, int n) {
    __shared__ int sdata[256];
    int base = blockIdx.x * 1024;
    int t = threadIdx.x;
    int v[4]; int s = 0;
    for (int j = 0; j < 4; ++j) {
        int i = base + t * 4 + j;
        v[j] = (i < n) ? deg[i] : 0;
        s += v[j];
    }
    sdata[t] = s;
    __syncthreads();
    for (int d2 = 1; d2 < 256; d2 <<= 1) {
        int x = (t >= d2) ? sdata[t - d2] : 0;
        __syncthreads();
        sdata[t] += x;
        __syncthreads();
    }
    int excl = sdata[t] - s;
    if (t == 255) partials[blockIdx.x] = sdata[255];
    int run = excl;
    for (int j = 0; j < 4; ++j) {
        int i = base + t * 4 + j;
        if (i < n) offs[i] = run;
        run += v[j];
    }
}

// pass2: exclusive scan of partials (single block, nparts <= 1024, 4/thread)
__global__ void scan2(int* __restrict__ partials, int nparts) {
    __shared__ int sdata[256];
    int t = threadIdx.x;
    int v[4]; int s = 0;
    for (int j = 0; j < 4; ++j) {
        int i = t * 4 + j;
        v[j] = (i < nparts) ? partials[i] : 0;
        s += v[j];
    }
    sdata[t] = s;
    __syncthreads();
    for (int d2 = 1; d2 < 256; d2 <<= 1) {
        int x = (t >= d2) ? sdata[t - d2] : 0;
        __syncthreads();
        sdata[t] += x;
        __syncthreads();
    }
    int excl = sdata[t] - s;
    int run = excl;
    for (int j = 0; j < 4; ++j) {
        int i = t * 4 + j;
        if (i < nparts) partials[i] = run;
        run += v[j];
    }
}

// pass3: add block offsets; also write the cursor copy (saves a memset + add in fill)
__global__ void scan3(int* __restrict__ offs, int* __restrict__ cur,
                      const int* __restrict__ partials, int n) {
    int i = blockIdx.x * blockDim.x + threadIdx.x;
    if (i < n) {
        int v = offs[i] + partials[i >> 10];
        offs[i] = v;
        cur[i] = v;
    }
}

// bucket[cur[g]++] = src[e]; 4 edges/thread, 4 independent atomic->write chains
__global__ void csr_fill_all(const int* __restrict__ csrc, const int* __restrict__ cdst,
                             const int* __restrict__ qsrc, const int* __restrict__ qdst,
                             const int* __restrict__ rcsrc, const int* __restrict__ rcdst,
                             const int* __restrict__ rqsrc, const int* __restrict__ rqdst,
                             int* __restrict__ curAll, int* __restrict__ bukAll) {
    int t = blockIdx.x * blockDim.x + threadIdx.x;
    if (t >= 4 * NE4_) return;
    int rel = t / NE4_;
    int er = (t - rel * NE4_) * 4;
    const int* srcs; const int* dsts; int base;
    if (rel == 0)      { srcs = csrc;  dsts = cdst;  base = 0; }
    else if (rel == 1) { srcs = qsrc;  dsts = qdst;  base = NP_; }
    else if (rel == 2) { srcs = rcsrc; dsts = rcdst; base = 2 * NP_; }
    else               { srcs = rqsrc; dsts = rqdst; base = 2 * NP_ + NQ_; }
    int4 d4 = *reinterpret_cast<const int4*>(dsts + er);
    int4 s4 = *reinterpret_cast<const int4*>(srcs + er);
    int p0 = atomicAdd(curAll + base + d4.x, 1);
    int p1 = atomicAdd(curAll + base + d4.y, 1);
    int p2 = atomicAdd(curAll + base + d4.z, 1);
    int p3 = atomicAdd(curAll + base + d4.w, 1);
    bukAll[p0] = s4.x;
    bukAll[p1] = s4.y;
    bukAll[p2] = s4.z;
    bukAll[p3] = s4.w;
}

// ---------------- gather-based mean aggregation, all 4 relations in one launch ----------------
// 4 dst rows per wave, 16 lanes per row, int4 (16B = 8 bf16) per lane.
// Neighbor loop unrolled x4 branchless (clamp+mask-fma): 16 independent row streams per wave.
__global__ __launch_bounds__(256, 8)
void gather_all(const bf16* __restrict__ hQ, const bf16* __restrict__ hP,
                const int* __restrict__ bukAll, const int* __restrict__ offAll,
                const int* __restrict__ degAll, bf16* __restrict__ meanAll) {
    const int tid = threadIdx.x;
    const int lane = tid & 63;
    const int g = lane >> 4;       // row-group within wave (0..3)
    const int li = lane & 15;      // lane within group: handles feats 8*li..8*li+7
    const int w = blockIdx.x * 16 + (tid >> 6) * 4 + g;  // dst row; grid sized exactly
    const bf16* h = (w < 2 * NP_) ? hQ : hP;  // P-dst relations source from Q, vice versa
    const int beg = offAll[w];
    const int cnt = degAll[w];

    float a0 = 0.f, a1 = 0.f, a2 = 0.f, a3 = 0.f, a4 = 0.f, a5 = 0.f, a6 = 0.f, a7 = 0.f;

    int myidx = (li < cnt) ? bukAll[beg + li] : 0;
    const int c16 = (cnt < 16) ? cnt : 16;
    const int last = c16 - 1;  // c16 > 0 whenever the loop runs
    for (int i = 0; i < c16; i += 4) {
#pragma unroll
        for (int j = 0; j < 4; ++j) {
            int idx = i + j;
            int src_lane = g * 16 + ((idx < c16) ? idx : last);
            float m = (idx < c16) ? 1.0f : 0.0f;
            int s_ = __shfl(myidx, src_lane);
            int4 v = reinterpret_cast<const int4*>(h + (size_t)s_ * 128)[li];
            unsigned u0 = (unsigned)v.x, u1 = (unsigned)v.y, u2 = (unsigned)v.z, u3 = (unsigned)v.w;
            a0 = fmaf(bfbits2f(u0 << 16), m, a0);
            a1 = fmaf(bfbits2f(u0 & 0xffff0000u), m, a1);
            a2 = fmaf(bfbits2f(u1 << 16), m, a2);
            a3 = fmaf(bfbits2f(u1 & 0xffff0000u), m, a3);
            a4 = fmaf(bfbits2f(u2 << 16), m, a4);
            a5 = fmaf(bfbits2f(u2 & 0xffff0000u), m, a5);
            a6 = fmaf(bfbits2f(u3 << 16), m, a6);
            a7 = fmaf(bfbits2f(u3 & 0xffff0000u), m, a7);
        }
    }
    for (int i = 16; i < cnt; ++i) {  // rare tail (deg > 16)
        int s_ = bukAll[beg + i];
        int4 v = reinterpret_cast<const int4*>(h + (size_t)s_ * 128)[li];
        unsigned u0 = (unsigned)v.x, u1 = (unsigned)v.y, u2 = (unsigned)v.z, u3 = (unsigned)v.w;
        a0 += bfbits2f(u0 << 16);
        a1 += bfbits2f(u0 & 0xffff0000u);
        a2 += bfbits2f(u1 << 16);
        a3 += bfbits2f(u1 & 0xffff0000u);
        a4 += bfbits2f(u2 << 16);
        a5 += bfbits2f(u2 & 0xffff0000u);
        a6 += bfbits2f(u3 << 16);
        a7 += bfbits2f(u3 & 0xffff0000u);
    }

    float r = (cnt > 0) ? (1.0f / (float)cnt) : 0.0f;
    unsigned o0 = ((unsigned)(unsigned short)f2bf_bits(a1 * r) << 16) | (unsigned short)f2bf_bits(a0 * r);
    unsigned o1 = ((unsigned)(unsigned short)f2bf_bits(a3 * r) << 16) | (unsigned short)f2bf_bits(a2 * r);
    unsigned o2 = ((unsigned)(unsigned short)f2bf_bits(a5 * r) << 16) | (unsigned short)f2bf_bits(a4 * r);
    unsigned o3 = ((unsigned)(unsigned short)f2bf_bits(a7 * r) << 16) | (unsigned short)f2bf_bits(a6 * r);
    int4 ov;
    ov.x = (int)o0; ov.y = (int)o1; ov.z = (int)o2; ov.w = (int)o3;
    reinterpret_cast<int4*>(meanAll + (size_t)w * 128)[li] = ov;
}

// ---------------- fused SAGE update (MFMA), P and Q in one launch ----------------
// out[i,:] = act( hdst[i,:]@W0 + mean1[i,:]@W1 + mean2[i,:]@W2 + bias )
// B-fragments read straight from global (L2-resident W): no lW staging -> LDS 17.4KB, 3 blocks/CU
template <typename OT>
__global__ __launch_bounds__(256, 3)
void sage_all(const bf16* __restrict__ hQin, const bf16* __restrict__ hPin,
              const bf16* __restrict__ meanAll, const bf16* __restrict__ WtL,
              const float* __restrict__ bsumL,
              OT* __restrict__ outQ, OT* __restrict__ outP,
              int do_relu, int nblkP) {
    __shared__ short lA[64 * 136];  // stride 136 shorts (272B: 16B-aligned)
    const int tid = threadIdx.x;
    const int wave = tid >> 6, lane = tid & 63;
    const int i16 = lane & 15, quad = lane >> 4;

    const bool isP = (int)blockIdx.x < nblkP;
    const int blk = isP ? blockIdx.x : blockIdx.x - nblkP;
    const int row0 = blk * 64;
    const int nrows = isP ? NP_ : NQ_;
    const bf16* hdst = isP ? hPin : hQin;
    const bf16* m1 = meanAll + (isP ? (size_t)0 : (size_t)(2 * NP_)) * 128;
    const bf16* m2 = meanAll + (isP ? (size_t)NP_ : (size_t)(2 * NP_ + NQ_)) * 128;
    const bf16* Wt3 = WtL + (size_t)(isP ? 0 : 3) * 16384;
    const float* bs = bsumL + (isP ? 0 : 128);
    OT* out = isP ? outP : outQ;

    facc4 acc[4][2];
    for (int nt = 0; nt < 2; ++nt) {
        float bv = bs[wave * 32 + nt * 16 + i16];
        for (int mt = 0; mt < 4; ++mt) {
            facc4 a = {bv, bv, bv, bv};
            acc[mt][nt] = a;
        }
    }

    const bf16* Asrc[3] = {hdst, m1, m2};
#pragma unroll
    for (int s = 0; s < 3; ++s) {
        __syncthreads();
        // stage A_s (64 x 128 bf16)
        {
            const bf16* A = Asrc[s];
            for (int j = 0; j < 4; ++j) {
                int c = j * 256 + tid;
                int r = c >> 4, k = (c & 15) * 8;
                int grow = row0 + r;
                int4 v = {0, 0, 0, 0};
                if (grow < nrows)
                    v = reinterpret_cast<const int4*>(A)[((size_t)grow * 128 + k) >> 3];
                *reinterpret_cast<int4*>(&lA[r * 136 + k]) = v;
            }
        }
        __syncthreads();
        const bf16* Ws = Wt3 + (size_t)s * 16384;
#pragma unroll
        for (int k0 = 0; k0 < 128; k0 += 32) {
            bfrag8 a[4], b[2];
            for (int mt = 0; mt < 4; ++mt)
                a[mt] = *reinterpret_cast<const bfrag8*>(&lA[(mt * 16 + i16) * 136 + k0 + quad * 8]);
            for (int nt = 0; nt < 2; ++nt)
                b[nt] = *reinterpret_cast<const bfrag8*>(
                    Ws + (size_t)(wave * 32 + nt * 16 + i16) * 128 + k0 + quad * 8);
            for (int mt = 0; mt < 4; ++mt)
                for (int nt = 0; nt < 2; ++nt)
                    acc[mt][nt] = __builtin_amdgcn_mfma_f32_16x16x32_bf16(a[mt], b[nt], acc[mt][nt], 0, 0, 0);
        }
    }

    for (int mt = 0; mt < 4; ++mt) {
        for (int nt = 0; nt < 2; ++nt) {
            int n = wave * 32 + nt * 16 + i16;
            for (int r = 0; r < 4; ++r) {
                int m = mt * 16 + quad * 4 + r;
                int grow = row0 + m;
                if (grow < nrows) {
                    float v = acc[mt][nt][r];
                    if (do_relu) v = fmaxf(v, 0.0f);
                    store_val(out + (size_t)grow * 128 + n, v);
                }
            }
        }
    }
}

// ---------------- launch ----------------

extern "C" void kernel_launch(void* const* d_in, const int* in_sizes, int n_in,
                              void* d_out, int out_size, void* d_ws, size_t ws_size,
                              hipStream_t stream) {
    const float* xq     = (const float*)d_in[0];
    const float* xp     = (const float*)d_in[1];
    const float* Wself  = (const float*)d_in[2];
    const float* Wneigh = (const float*)d_in[3];
    const float* bias   = (const float*)d_in[4];
    const int* csrc  = (const int*)d_in[5];
    const int* cdst  = (const int*)d_in[6];
    const int* qsrc  = (const int*)d_in[7];
    const int* qdst  = (const int*)d_in[8];
    const int* rcsrc = (const int*)d_in[9];
    const int* rcdst = (const int*)d_in[10];
    const int* rqsrc = (const int*)d_in[11];
    const int* rqdst = (const int*)d_in[12];

    const int NDST = 2 * NP_ + 2 * NQ_;  // 600000 concatenated dst rows

    char* w = (char*)d_ws;
    bf16* xqb    = (bf16*)w;  w += (size_t)NQ_ * 128 * 2;
    bf16* xpb    = (bf16*)w;  w += (size_t)NP_ * 128 * 2;
    bf16* hQ1    = (bf16*)w;  w += (size_t)NQ_ * 128 * 2;
    bf16* hP1    = (bf16*)w;  w += (size_t)NP_ * 128 * 2;
    bf16* meanAll = (bf16*)w; w += (size_t)NDST * 128 * 2;
    bf16* Wt     = (bf16*)w;  w += (size_t)12 * 16384 * 2;
    float* bsum  = (float*)w; w += 512 * 4;
    int* degAll  = (int*)w;   w += (size_t)NDST * 4;
    int* offAll  = (int*)w;   w += (size_t)NDST * 4;
    int* curAll  = (int*)w;   w += (size_t)NDST * 4;
    int* bukAll  = (int*)w;   w += (size_t)4 * NE_ * 4;
    int* partials = (int*)w;  w += 1024 * 4;

    float* outQ = (float*)d_out;
    float* outP = outQ + (size_t)NQ_ * 128;

    // --- one-time prep ---
    cast_all<<<((NQ_ + NP_) * 32 + 255) / 256, 256, 0, stream>>>(xq, xp, xqb, xpb);
    prep_weights<<<768, 256, 0, stream>>>(Wself, Wneigh, Wt);
    prep_bias<<<2, 256, 0, stream>>>(bias, bsum);

    // --- concatenated CSR build (one pass for all 4 relations) ---
    hipMemsetAsync(degAll, 0, (size_t)NDST * 4, stream);
    deg_count_all<<<(4 * NE4_ + 255) / 256, 256, 0, stream>>>(cdst, qdst, rcdst, rqdst, degAll);
    int nparts = (NDST + 1023) / 1024;  // 586
    scan1<<<nparts, 256, 0, stream>>>(degAll, offAll, partials, NDST);
    scan2<<<1, 256, 0, stream>>>(partials, nparts);
    scan3<<<(NDST + 255) / 256, 256, 0, stream>>>(offAll, curAll, partials, NDST);
    csr_fill_all<<<(4 * NE4_ + 255) / 256, 256, 0, stream>>>(csrc, cdst, qsrc, qdst,
                                                             rcsrc, rcdst, rqsrc, rqdst,
                                                             curAll, bukAll);

    const int nblkP = (NP_ + 63) / 64;            // 3125
    const int nblkQ = (NQ_ + 63) / 64;            // 1563
    const int gather_blocks = NDST / 16;          // 37500 (exact: 16 rows per block)

    for (int l = 0; l < 2; ++l) {
        const bf16* hQin = l ? hQ1 : xqb;
        const bf16* hPin = l ? hP1 : xpb;
        const bf16* WtL = Wt + (size_t)l * 6 * 16384;
        const float* bL = bsum + l * 256;

        gather_all<<<gather_blocks, 256, 0, stream>>>(hQin, hPin, bukAll, offAll, degAll, meanAll);

        if (l == 0)
            sage_all<bf16><<<nblkP + nblkQ, 256, 0, stream>>>(hQin, hPin, meanAll, WtL, bL,
                                                              hQ1, hP1, 1, nblkP);
        else
            sage_all<float><<<nblkP + nblkQ, 256, 0, stream>>>(hQin, hPin, meanAll, WtL, bL,
                                                               outQ, outP, 0, nblkP);
    }
}

// Round 4
// 781.259 us; speedup vs baseline: 1.4351x; 1.1489x over previous
//
#include <hip/hip_runtime.h>
#include <hip/hip_bf16.h>

typedef __hip_bfloat16 bf16;
typedef __attribute__((ext_vector_type(8))) short bfrag8;
typedef __attribute__((ext_vector_type(4))) float facc4;

#define NQ_ 100000
#define NP_ 200000
#define NE_ 500000

// grid split constants for fused kernels
#define CAST_BLOCKS 37500   // ((NQ_+NP_)*32) / 256 exactly
#define EDGE_BLOCKS 7813    // ceil(4*NE_ / 256)
#define PREPW_BLOCKS 768    // 12*16384 / 256
#define PREPB_BLOCKS 2      // 512 / 256

static __device__ __forceinline__ short f2bf_bits(float f) {
    bf16 h = __float2bfloat16(f);
    short r;
    __builtin_memcpy(&r, &h, 2);
    return r;
}

static __device__ __forceinline__ float bfbits2f(unsigned u) {
    return __builtin_bit_cast(float, u);
}

static __device__ __forceinline__ void store_val(bf16* p, float v) { *p = __float2bfloat16(v); }
static __device__ __forceinline__ void store_val(float* p, float v) { *p = v; }

// ---------------- fused: fp32->bf16 cast (BW-bound) + deg+rank count (latency-bound) ----------
// Blocks [0, CAST_BLOCKS): cast both feature tables.
// Blocks [CAST_BLOCKS, CAST_BLOCKS+EDGE_BLOCKS): rank[e] = atomicAdd(deg + dst[e], 1).
// Co-residency lets the cast blocks soak idle BW while edge blocks wait on atomic round trips.
__global__ void fused_cast_deg(const float* __restrict__ xq, const float* __restrict__ xp,
                               bf16* __restrict__ xqb, bf16* __restrict__ xpb,
                               const int* __restrict__ cdst, const int* __restrict__ qdst,
                               const int* __restrict__ rcdst, const int* __restrict__ rqdst,
                               int* __restrict__ degAll, int* __restrict__ rankAll) {
    if ((int)blockIdx.x < CAST_BLOCKS) {
        int i = blockIdx.x * blockDim.x + threadIdx.x;
        const int nq4 = NQ_ * 32;
        float4 v;
        short4 o;
        if (i < nq4) {
            v = reinterpret_cast<const float4*>(xq)[i];
            o.x = f2bf_bits(v.x); o.y = f2bf_bits(v.y); o.z = f2bf_bits(v.z); o.w = f2bf_bits(v.w);
            reinterpret_cast<short4*>(xqb)[i] = o;
        } else {
            int j = i - nq4;  // j < NP_*32 guaranteed by grid sizing
            v = reinterpret_cast<const float4*>(xp)[j];
            o.x = f2bf_bits(v.x); o.y = f2bf_bits(v.y); o.z = f2bf_bits(v.z); o.w = f2bf_bits(v.w);
            reinterpret_cast<short4*>(xpb)[j] = o;
        }
        return;
    }
    int e = (blockIdx.x - CAST_BLOCKS) * blockDim.x + threadIdx.x;
    if (e >= 4 * NE_) return;
    int rel = e / NE_;
    int er = e - rel * NE_;
    int d, base;
    if (rel == 0)      { d = cdst[er];  base = 0; }
    else if (rel == 1) { d = qdst[er];  base = NP_; }
    else if (rel == 2) { d = rcdst[er]; base = 2 * NP_; }
    else               { d = rqdst[er]; base = 2 * NP_ + NQ_; }
    rankAll[e] = atomicAdd(degAll + base + d, 1);
}

// ---------------- scans over degAll -> offAll ----------------

// pass1: per-block (1024 elems) exclusive scan -> offs, block total -> partials
__global__ void scan1(const int* __restrict__ deg, int* __restrict__ offs,
                      int* __restrict__ partials, int n) {
    __shared__ int sdata[256];
    int base = blockIdx.x * 1024;
    int t = threadIdx.x;
    int v[4]; int s = 0;
    for (int j = 0; j < 4; ++j) {
        int i = base + t * 4 + j;
        v[j] = (i < n) ? deg[i] : 0;
        s += v[j];
    }
    sdata[t] = s;
    __syncthreads();
    for (int d2 = 1; d2 < 256; d2 <<= 1) {
        int x = (t >= d2) ? sdata[t - d2] : 0;
        __syncthreads();
        sdata[t] += x;
        __syncthreads();
    }
    int excl = sdata[t] - s;
    if (t == 255) partials[blockIdx.x] = sdata[255];
    int run = excl;
    for (int j = 0; j < 4; ++j) {
        int i = base + t * 4 + j;
        if (i < n) offs[i] = run;
        run += v[j];
    }
}

// pass2: exclusive scan of partials (single block, nparts <= 1024, 4/thread)
__global__ void scan2(int* __restrict__ partials, int nparts) {
    __shared__ int sdata[256];
    int t = threadIdx.x;
    int v[4]; int s = 0;
    for (int j = 0; j < 4; ++j) {
        int i = t * 4 + j;
        v[j] = (i < nparts) ? partials[i] : 0;
        s += v[j];
    }
    sdata[t] = s;
    __syncthreads();
    for (int d2 = 1; d2 < 256; d2 <<= 1) {
        int x = (t >= d2) ? sdata[t - d2] : 0;
        __syncthreads();
        sdata[t] += x;
        __syncthreads();
    }
    int excl = sdata[t] - s;
    int run = excl;
    for (int j = 0; j < 4; ++j) {
        int i = t * 4 + j;
        if (i < nparts) partials[i] = run;
        run += v[j];
    }
}

// pass3: add block offsets
__global__ void scan3(int* __restrict__ offs, const int* __restrict__ partials, int n) {
    int i = blockIdx.x * blockDim.x + threadIdx.x;
    if (i < n) offs[i] += partials[i >> 10];
}

// ---------------- fused: atomic-free CSR fill + weight/bias prep ----------------
// Blocks [0, EDGE_BLOCKS): buk[off[d] + rank[e]] = src[e]  (loads + fire-and-forget scatter)
// Blocks [EDGE_BLOCKS, +PREPW_BLOCKS): combine+transpose weights -> bf16 Wt
// Last PREPB_BLOCKS: bias sums
__global__ void fused_fill_prep(const int* __restrict__ csrc, const int* __restrict__ cdst,
                                const int* __restrict__ qsrc, const int* __restrict__ qdst,
                                const int* __restrict__ rcsrc, const int* __restrict__ rcdst,
                                const int* __restrict__ rqsrc, const int* __restrict__ rqdst,
                                const int* __restrict__ offAll, const int* __restrict__ rankAll,
                                int* __restrict__ bukAll,
                                const float* __restrict__ Wself, const float* __restrict__ Wneigh,
                                bf16* __restrict__ Wt,
                                const float* __restrict__ bias, float* __restrict__ bsum) {
    if ((int)blockIdx.x < EDGE_BLOCKS) {
        int e = blockIdx.x * blockDim.x + threadIdx.x;
        if (e >= 4 * NE_) return;
        int rel = e / NE_;
        int er = e - rel * NE_;
        int d, s, base;
        if (rel == 0)      { d = cdst[er];  s = csrc[er];  base = 0; }
        else if (rel == 1) { d = qdst[er];  s = qsrc[er];  base = NP_; }
        else if (rel == 2) { d = rcdst[er]; s = rcsrc[er]; base = 2 * NP_; }
        else               { d = rqdst[er]; s = rqsrc[er]; base = 2 * NP_ + NQ_; }
        bukAll[offAll[base + d] + rankAll[e]] = s;
        return;
    }
    if ((int)blockIdx.x < EDGE_BLOCKS + PREPW_BLOCKS) {
        int g = (blockIdx.x - EDGE_BLOCKS) * blockDim.x + threadIdx.x;
        int m = g >> 14;
        int rem = g & 16383;
        int n = rem >> 7, k = rem & 127;
        int l = m / 6, t = (m / 3) % 2, s = m % 3;
        int rA = (t == 0) ? 0 : 1;
        int rB = (t == 0) ? 3 : 2;
        float v;
        if (s == 0) {
            v = Wself[((size_t)(l * 4 + rA) * 128 + k) * 128 + n]
              + Wself[((size_t)(l * 4 + rB) * 128 + k) * 128 + n];
        } else {
            int r = (s == 1) ? rA : rB;
            v = Wneigh[((size_t)(l * 4 + r) * 128 + k) * 128 + n];
        }
        Wt[(size_t)m * 16384 + n * 128 + k] = __float2bfloat16(v);
        return;
    }
    {
        int g = (blockIdx.x - EDGE_BLOCKS - PREPW_BLOCKS) * blockDim.x + threadIdx.x;
        if (g >= 512) return;
        int l = g >> 8, t = (g >> 7) & 1, n = g & 127;
        int rA = (t == 0) ? 0 : 1;
        int rB = (t == 0) ? 3 : 2;
        bsum[g] = bias[(l * 4 + rA) * 128 + n] + bias[(l * 4 + rB) * 128 + n];
    }
}

// ---------------- gather-based mean aggregation, all 4 relations in one launch ----------------
// 4 dst rows per wave, 16 lanes per row, int4 (16B = 8 bf16) per lane.
// Neighbor loop unrolled x4 branchless (clamp+mask-fma): 16 independent row streams per wave.
__global__ __launch_bounds__(256, 8)
void gather_all(const bf16* __restrict__ hQ, const bf16* __restrict__ hP,
                const int* __restrict__ bukAll, const int* __restrict__ offAll,
                const int* __restrict__ degAll, bf16* __restrict__ meanAll) {
    const int tid = threadIdx.x;
    const int lane = tid & 63;
    const int g = lane >> 4;       // row-group within wave (0..3)
    const int li = lane & 15;      // lane within group: handles feats 8*li..8*li+7
    const int w = blockIdx.x * 16 + (tid >> 6) * 4 + g;  // dst row; grid sized exactly
    const bf16* h = (w < 2 * NP_) ? hQ : hP;  // P-dst relations source from Q, vice versa
    const int beg = offAll[w];
    const int cnt = degAll[w];

    float a0 = 0.f, a1 = 0.f, a2 = 0.f, a3 = 0.f, a4 = 0.f, a5 = 0.f, a6 = 0.f, a7 = 0.f;

    int myidx = (li < cnt) ? bukAll[beg + li] : 0;
    const int c16 = (cnt < 16) ? cnt : 16;
    const int last = c16 - 1;  // c16 > 0 whenever the loop runs
    for (int i = 0; i < c16; i += 4) {
#pragma unroll
        for (int j = 0; j < 4; ++j) {
            int idx = i + j;
            int src_lane = g * 16 + ((idx < c16) ? idx : last);
            float m = (idx < c16) ? 1.0f : 0.0f;
            int s_ = __shfl(myidx, src_lane);
            int4 v = reinterpret_cast<const int4*>(h + (size_t)s_ * 128)[li];
            unsigned u0 = (unsigned)v.x, u1 = (unsigned)v.y, u2 = (unsigned)v.z, u3 = (unsigned)v.w;
            a0 = fmaf(bfbits2f(u0 << 16), m, a0);
            a1 = fmaf(bfbits2f(u0 & 0xffff0000u), m, a1);
            a2 = fmaf(bfbits2f(u1 << 16), m, a2);
            a3 = fmaf(bfbits2f(u1 & 0xffff0000u), m, a3);
            a4 = fmaf(bfbits2f(u2 << 16), m, a4);
            a5 = fmaf(bfbits2f(u2 & 0xffff0000u), m, a5);
            a6 = fmaf(bfbits2f(u3 << 16), m, a6);
            a7 = fmaf(bfbits2f(u3 & 0xffff0000u), m, a7);
        }
    }
    for (int i = 16; i < cnt; ++i) {  // rare tail (deg > 16)
        int s_ = bukAll[beg + i];
        int4 v = reinterpret_cast<const int4*>(h + (size_t)s_ * 128)[li];
        unsigned u0 = (unsigned)v.x, u1 = (unsigned)v.y, u2 = (unsigned)v.z, u3 = (unsigned)v.w;
        a0 += bfbits2f(u0 << 16);
        a1 += bfbits2f(u0 & 0xffff0000u);
        a2 += bfbits2f(u1 << 16);
        a3 += bfbits2f(u1 & 0xffff0000u);
        a4 += bfbits2f(u2 << 16);
        a5 += bfbits2f(u2 & 0xffff0000u);
        a6 += bfbits2f(u3 << 16);
        a7 += bfbits2f(u3 & 0xffff0000u);
    }

    float r = (cnt > 0) ? (1.0f / (float)cnt) : 0.0f;
    unsigned o0 = ((unsigned)(unsigned short)f2bf_bits(a1 * r) << 16) | (unsigned short)f2bf_bits(a0 * r);
    unsigned o1 = ((unsigned)(unsigned short)f2bf_bits(a3 * r) << 16) | (unsigned short)f2bf_bits(a2 * r);
    unsigned o2 = ((unsigned)(unsigned short)f2bf_bits(a5 * r) << 16) | (unsigned short)f2bf_bits(a4 * r);
    unsigned o3 = ((unsigned)(unsigned short)f2bf_bits(a7 * r) << 16) | (unsigned short)f2bf_bits(a6 * r);
    int4 ov;
    ov.x = (int)o0; ov.y = (int)o1; ov.z = (int)o2; ov.w = (int)o3;
    reinterpret_cast<int4*>(meanAll + (size_t)w * 128)[li] = ov;
}

// ---------------- fused SAGE update (MFMA), P and Q in one launch ----------------
// out[i,:] = act( hdst[i,:]@W0 + mean1[i,:]@W1 + mean2[i,:]@W2 + bias )
// B-fragments read straight from global (L2-resident W): no lW staging -> LDS 17.4KB, 3 blocks/CU
template <typename OT>
__global__ __launch_bounds__(256, 3)
void sage_all(const bf16* __restrict__ hQin, const bf16* __restrict__ hPin,
              const bf16* __restrict__ meanAll, const bf16* __restrict__ WtL,
              const float* __restrict__ bsumL,
              OT* __restrict__ outQ, OT* __restrict__ outP,
              int do_relu, int nblkP) {
    __shared__ short lA[64 * 136];  // stride 136 shorts (272B: 16B-aligned)
    const int tid = threadIdx.x;
    const int wave = tid >> 6, lane = tid & 63;
    const int i16 = lane & 15, quad = lane >> 4;

    const bool isP = (int)blockIdx.x < nblkP;
    const int blk = isP ? blockIdx.x : blockIdx.x - nblkP;
    const int row0 = blk * 64;
    const int nrows = isP ? NP_ : NQ_;
    const bf16* hdst = isP ? hPin : hQin;
    const bf16* m1 = meanAll + (isP ? (size_t)0 : (size_t)(2 * NP_)) * 128;
    const bf16* m2 = meanAll + (isP ? (size_t)NP_ : (size_t)(2 * NP_ + NQ_)) * 128;
    const bf16* Wt3 = WtL + (size_t)(isP ? 0 : 3) * 16384;
    const float* bs = bsumL + (isP ? 0 : 128);
    OT* out = isP ? outP : outQ;

    facc4 acc[4][2];
    for (int nt = 0; nt < 2; ++nt) {
        float bv = bs[wave * 32 + nt * 16 + i16];
        for (int mt = 0; mt < 4; ++mt) {
            facc4 a = {bv, bv, bv, bv};
            acc[mt][nt] = a;
        }
    }

    const bf16* Asrc[3] = {hdst, m1, m2};
#pragma unroll
    for (int s = 0; s < 3; ++s) {
        __syncthreads();
        // stage A_s (64 x 128 bf16)
        {
            const bf16* A = Asrc[s];
            for (int j = 0; j < 4; ++j) {
                int c = j * 256 + tid;
                int r = c >> 4, k = (c & 15) * 8;
                int grow = row0 + r;
                int4 v = {0, 0, 0, 0};
                if (grow < nrows)
                    v = reinterpret_cast<const int4*>(A)[((size_t)grow * 128 + k) >> 3];
                *reinterpret_cast<int4*>(&lA[r * 136 + k]) = v;
            }
        }
        __syncthreads();
        const bf16* Ws = Wt3 + (size_t)s * 16384;
#pragma unroll
        for (int k0 = 0; k0 < 128; k0 += 32) {
            bfrag8 a[4], b[2];
            for (int mt = 0; mt < 4; ++mt)
                a[mt] = *reinterpret_cast<const bfrag8*>(&lA[(mt * 16 + i16) * 136 + k0 + quad * 8]);
            for (int nt = 0; nt < 2; ++nt)
                b[nt] = *reinterpret_cast<const bfrag8*>(
                    Ws + (size_t)(wave * 32 + nt * 16 + i16) * 128 + k0 + quad * 8);
            for (int mt = 0; mt < 4; ++mt)
                for (int nt = 0; nt < 2; ++nt)
                    acc[mt][nt] = __builtin_amdgcn_mfma_f32_16x16x32_bf16(a[mt], b[nt], acc[mt][nt], 0, 0, 0);
        }
    }

    for (int mt = 0; mt < 4; ++mt) {
        for (int nt = 0; nt < 2; ++nt) {
            int n = wave * 32 + nt * 16 + i16;
            for (int r = 0; r < 4; ++r) {
                int m = mt * 16 + quad * 4 + r;
                int grow = row0 + m;
                if (grow < nrows) {
                    float v = acc[mt][nt][r];
                    if (do_relu) v = fmaxf(v, 0.0f);
                    store_val(out + (size_t)grow * 128 + n, v);
                }
            }
        }
    }
}

// ---------------- launch ----------------

extern "C" void kernel_launch(void* const* d_in, const int* in_sizes, int n_in,
                              void* d_out, int out_size, void* d_ws, size_t ws_size,
                              hipStream_t stream) {
    const float* xq     = (const float*)d_in[0];
    const float* xp     = (const float*)d_in[1];
    const float* Wself  = (const float*)d_in[2];
    const float* Wneigh = (const float*)d_in[3];
    const float* bias   = (const float*)d_in[4];
    const int* csrc  = (const int*)d_in[5];
    const int* cdst  = (const int*)d_in[6];
    const int* qsrc  = (const int*)d_in[7];
    const int* qdst  = (const int*)d_in[8];
    const int* rcsrc = (const int*)d_in[9];
    const int* rcdst = (const int*)d_in[10];
    const int* rqsrc = (const int*)d_in[11];
    const int* rqdst = (const int*)d_in[12];

    const int NDST = 2 * NP_ + 2 * NQ_;  // 600000 concatenated dst rows

    char* w = (char*)d_ws;
    bf16* xqb    = (bf16*)w;  w += (size_t)NQ_ * 128 * 2;
    bf16* xpb    = (bf16*)w;  w += (size_t)NP_ * 128 * 2;
    bf16* hQ1    = (bf16*)w;  w += (size_t)NQ_ * 128 * 2;
    bf16* hP1    = (bf16*)w;  w += (size_t)NP_ * 128 * 2;
    bf16* meanAll = (bf16*)w; w += (size_t)NDST * 128 * 2;
    bf16* Wt     = (bf16*)w;  w += (size_t)12 * 16384 * 2;
    float* bsum  = (float*)w; w += 512 * 4;
    int* degAll  = (int*)w;   w += (size_t)NDST * 4;
    int* offAll  = (int*)w;   w += (size_t)NDST * 4;
    int* rankAll = (int*)w;   w += (size_t)4 * NE_ * 4;
    int* bukAll  = (int*)w;   w += (size_t)4 * NE_ * 4;
    int* partials = (int*)w;  w += 1024 * 4;

    float* outQ = (float*)d_out;
    float* outP = outQ + (size_t)NQ_ * 128;

    // --- prep + CSR build ---
    hipMemsetAsync(degAll, 0, (size_t)NDST * 4, stream);
    fused_cast_deg<<<CAST_BLOCKS + EDGE_BLOCKS, 256, 0, stream>>>(
        xq, xp, xqb, xpb, cdst, qdst, rcdst, rqdst, degAll, rankAll);
    int nparts = (NDST + 1023) / 1024;  // 586
    scan1<<<nparts, 256, 0, stream>>>(degAll, offAll, partials, NDST);
    scan2<<<1, 256, 0, stream>>>(partials, nparts);
    scan3<<<(NDST + 255) / 256, 256, 0, stream>>>(offAll, partials, NDST);
    fused_fill_prep<<<EDGE_BLOCKS + PREPW_BLOCKS + PREPB_BLOCKS, 256, 0, stream>>>(
        csrc, cdst, qsrc, qdst, rcsrc, rcdst, rqsrc, rqdst,
        offAll, rankAll, bukAll, Wself, Wneigh, Wt, bias, bsum);

    const int nblkP = (NP_ + 63) / 64;            // 3125
    const int nblkQ = (NQ_ + 63) / 64;            // 1563
    const int gather_blocks = NDST / 16;          // 37500 (exact: 16 rows per block)

    for (int l = 0; l < 2; ++l) {
        const bf16* hQin = l ? hQ1 : xqb;
        const bf16* hPin = l ? hP1 : xpb;
        const bf16* WtL = Wt + (size_t)l * 6 * 16384;
        const float* bL = bsum + l * 256;

        gather_all<<<gather_blocks, 256, 0, stream>>>(hQin, hPin, bukAll, offAll, degAll, meanAll);

        if (l == 0)
            sage_all<bf16><<<nblkP + nblkQ, 256, 0, stream>>>(hQin, hPin, meanAll, WtL, bL,
                                                              hQ1, hP1, 1, nblkP);
        else
            sage_all<float><<<nblkP + nblkQ, 256, 0, stream>>>(hQin, hPin, meanAll, WtL, bL,
                                                               outQ, outP, 0, nblkP);
    }
}

// Round 5
// 739.657 us; speedup vs baseline: 1.5158x; 1.0562x over previous
//
#include <hip/hip_runtime.h>
#include <hip/hip_bf16.h>

typedef __hip_bfloat16 bf16;
typedef __attribute__((ext_vector_type(8))) short bfrag8;
typedef __attribute__((ext_vector_type(4))) float facc4;

#define NQ_ 100000
#define NP_ 200000
#define NE_ 500000

#define EDGE_TOTAL (4 * NE_)            // 2,000,000 edges
#define CAST_TOTAL ((NQ_ + NP_) * 32)   // 9,600,000 float4 elements
#define EDGE_BLOCKS 7813                // ceil(EDGE_TOTAL / 256)
#define PREPW_BLOCKS 768                // 12*16384 / 256
#define PREPB_BLOCKS 2                  // 512 / 256

static __device__ __forceinline__ short f2bf_bits(float f) {
    bf16 h = __float2bfloat16(f);
    short r;
    __builtin_memcpy(&r, &h, 2);
    return r;
}

static __device__ __forceinline__ float bfbits2f(unsigned u) {
    return __builtin_bit_cast(float, u);
}

static __device__ __forceinline__ void store_val(bf16* p, float v) { *p = __float2bfloat16(v); }
static __device__ __forceinline__ void store_val(float* p, float v) { *p = v; }

// ---------------- fused: deg+rank atomic with thread-level cast overlap ----------------
// Each thread owns ONE edge (issue atomicAdd first) and ~5 float4 cast elements
// (independent load->convert->store chains that execute while the atomic is in flight).
// The rank store -- the only consumer of the atomic's return value -- goes last.
__global__ __launch_bounds__(256, 8)
void fused_cast_deg(const float* __restrict__ xq, const float* __restrict__ xp,
                    bf16* __restrict__ xqb, bf16* __restrict__ xpb,
                    const int* __restrict__ cdst, const int* __restrict__ qdst,
                    const int* __restrict__ rcdst, const int* __restrict__ rqdst,
                    int* __restrict__ degAll, int* __restrict__ rankAll) {
    const int e = blockIdx.x * blockDim.x + threadIdx.x;
    const bool has_edge = (e < EDGE_TOTAL);

    int rank = 0;
    if (has_edge) {
        int rel = e / NE_;
        int er = e - rel * NE_;
        int d, base;
        if (rel == 0)      { d = cdst[er];  base = 0; }
        else if (rel == 1) { d = qdst[er];  base = NP_; }
        else if (rel == 2) { d = rcdst[er]; base = 2 * NP_; }
        else               { d = rqdst[er]; base = 2 * NP_ + NQ_; }
        rank = atomicAdd(degAll + base + d, 1);   // long-latency; hidden by cast work below
    }

    const int nq4 = NQ_ * 32;
#pragma unroll
    for (int k = 0; k < 5; ++k) {
        int i = e + k * EDGE_TOTAL;
        if (i < CAST_TOTAL) {
            float4 v;
            short4 o;
            if (i < nq4) {
                v = reinterpret_cast<const float4*>(xq)[i];
                o.x = f2bf_bits(v.x); o.y = f2bf_bits(v.y); o.z = f2bf_bits(v.z); o.w = f2bf_bits(v.w);
                reinterpret_cast<short4*>(xqb)[i] = o;
            } else {
                int j = i - nq4;
                v = reinterpret_cast<const float4*>(xp)[j];
                o.x = f2bf_bits(v.x); o.y = f2bf_bits(v.y); o.z = f2bf_bits(v.z); o.w = f2bf_bits(v.w);
                reinterpret_cast<short4*>(xpb)[j] = o;
            }
        }
    }

    if (has_edge) rankAll[e] = rank;   // waitcnt on the atomic lands here, after cast issues
}

// ---------------- scans over degAll -> offAll ----------------

// pass1: per-block (1024 elems) exclusive scan -> offs, block total -> partials
__global__ void scan1(const int* __restrict__ deg, int* __restrict__ offs,
                      int* __restrict__ partials, int n) {
    __shared__ int sdata[256];
    int base = blockIdx.x * 1024;
    int t = threadIdx.x;
    int v[4]; int s = 0;
    for (int j = 0; j < 4; ++j) {
        int i = base + t * 4 + j;
        v[j] = (i < n) ? deg[i] : 0;
        s += v[j];
    }
    sdata[t] = s;
    __syncthreads();
    for (int d2 = 1; d2 < 256; d2 <<= 1) {
        int x = (t >= d2) ? sdata[t - d2] : 0;
        __syncthreads();
        sdata[t] += x;
        __syncthreads();
    }
    int excl = sdata[t] - s;
    if (t == 255) partials[blockIdx.x] = sdata[255];
    int run = excl;
    for (int j = 0; j < 4; ++j) {
        int i = base + t * 4 + j;
        if (i < n) offs[i] = run;
        run += v[j];
    }
}

// pass2: exclusive scan of partials (single block, nparts <= 1024, 4/thread)
__global__ void scan2(int* __restrict__ partials, int nparts) {
    __shared__ int sdata[256];
    int t = threadIdx.x;
    int v[4]; int s = 0;
    for (int j = 0; j < 4; ++j) {
        int i = t * 4 + j;
        v[j] = (i < nparts) ? partials[i] : 0;
        s += v[j];
    }
    sdata[t] = s;
    __syncthreads();
    for (int d2 = 1; d2 < 256; d2 <<= 1) {
        int x = (t >= d2) ? sdata[t - d2] : 0;
        __syncthreads();
        sdata[t] += x;
        __syncthreads();
    }
    int excl = sdata[t] - s;
    int run = excl;
    for (int j = 0; j < 4; ++j) {
        int i = t * 4 + j;
        if (i < nparts) partials[i] = run;
        run += v[j];
    }
}

// pass3: add block offsets
__global__ void scan3(int* __restrict__ offs, const int* __restrict__ partials, int n) {
    int i = blockIdx.x * blockDim.x + threadIdx.x;
    if (i < n) offs[i] += partials[i >> 10];
}

// ---------------- fused: atomic-free CSR fill + weight/bias prep ----------------
// Blocks [0, EDGE_BLOCKS): buk[off[d] + rank[e]] = src[e]  (loads + fire-and-forget scatter)
// Blocks [EDGE_BLOCKS, +PREPW_BLOCKS): combine+transpose weights -> bf16 Wt
// Last PREPB_BLOCKS: bias sums
__global__ void fused_fill_prep(const int* __restrict__ csrc, const int* __restrict__ cdst,
                                const int* __restrict__ qsrc, const int* __restrict__ qdst,
                                const int* __restrict__ rcsrc, const int* __restrict__ rcdst,
                                const int* __restrict__ rqsrc, const int* __restrict__ rqdst,
                                const int* __restrict__ offAll, const int* __restrict__ rankAll,
                                int* __restrict__ bukAll,
                                const float* __restrict__ Wself, const float* __restrict__ Wneigh,
                                bf16* __restrict__ Wt,
                                const float* __restrict__ bias, float* __restrict__ bsum) {
    if ((int)blockIdx.x < EDGE_BLOCKS) {
        int e = blockIdx.x * blockDim.x + threadIdx.x;
        if (e >= EDGE_TOTAL) return;
        int rel = e / NE_;
        int er = e - rel * NE_;
        int d, s, base;
        if (rel == 0)      { d = cdst[er];  s = csrc[er];  base = 0; }
        else if (rel == 1) { d = qdst[er];  s = qsrc[er];  base = NP_; }
        else if (rel == 2) { d = rcdst[er]; s = rcsrc[er]; base = 2 * NP_; }
        else               { d = rqdst[er]; s = rqsrc[er]; base = 2 * NP_ + NQ_; }
        bukAll[offAll[base + d] + rankAll[e]] = s;
        return;
    }
    if ((int)blockIdx.x < EDGE_BLOCKS + PREPW_BLOCKS) {
        int g = (blockIdx.x - EDGE_BLOCKS) * blockDim.x + threadIdx.x;
        int m = g >> 14;
        int rem = g & 16383;
        int n = rem >> 7, k = rem & 127;
        int l = m / 6, t = (m / 3) % 2, s = m % 3;
        int rA = (t == 0) ? 0 : 1;
        int rB = (t == 0) ? 3 : 2;
        float v;
        if (s == 0) {
            v = Wself[((size_t)(l * 4 + rA) * 128 + k) * 128 + n]
              + Wself[((size_t)(l * 4 + rB) * 128 + k) * 128 + n];
        } else {
            int r = (s == 1) ? rA : rB;
            v = Wneigh[((size_t)(l * 4 + r) * 128 + k) * 128 + n];
        }
        Wt[(size_t)m * 16384 + n * 128 + k] = __float2bfloat16(v);
        return;
    }
    {
        int g = (blockIdx.x - EDGE_BLOCKS - PREPW_BLOCKS) * blockDim.x + threadIdx.x;
        if (g >= 512) return;
        int l = g >> 8, t = (g >> 7) & 1, n = g & 127;
        int rA = (t == 0) ? 0 : 1;
        int rB = (t == 0) ? 3 : 2;
        bsum[g] = bias[(l * 4 + rA) * 128 + n] + bias[(l * 4 + rB) * 128 + n];
    }
}

// ---------------- gather-based mean aggregation, all 4 relations in one launch ----------------
// 4 dst rows per wave, 16 lanes per row, int4 (16B = 8 bf16) per lane.
// Neighbor loop unrolled x4 branchless (clamp+mask-fma): 16 independent row streams per wave.
__global__ __launch_bounds__(256, 8)
void gather_all(const bf16* __restrict__ hQ, const bf16* __restrict__ hP,
                const int* __restrict__ bukAll, const int* __restrict__ offAll,
                const int* __restrict__ degAll, bf16* __restrict__ meanAll) {
    const int tid = threadIdx.x;
    const int lane = tid & 63;
    const int g = lane >> 4;       // row-group within wave (0..3)
    const int li = lane & 15;      // lane within group: handles feats 8*li..8*li+7
    const int w = blockIdx.x * 16 + (tid >> 6) * 4 + g;  // dst row; grid sized exactly
    const bf16* h = (w < 2 * NP_) ? hQ : hP;  // P-dst relations source from Q, vice versa
    const int beg = offAll[w];
    const int cnt = degAll[w];

    float a0 = 0.f, a1 = 0.f, a2 = 0.f, a3 = 0.f, a4 = 0.f, a5 = 0.f, a6 = 0.f, a7 = 0.f;

    int myidx = (li < cnt) ? bukAll[beg + li] : 0;
    const int c16 = (cnt < 16) ? cnt : 16;
    const int last = c16 - 1;  // c16 > 0 whenever the loop runs
    for (int i = 0; i < c16; i += 4) {
#pragma unroll
        for (int j = 0; j < 4; ++j) {
            int idx = i + j;
            int src_lane = g * 16 + ((idx < c16) ? idx : last);
            float m = (idx < c16) ? 1.0f : 0.0f;
            int s_ = __shfl(myidx, src_lane);
            int4 v = reinterpret_cast<const int4*>(h + (size_t)s_ * 128)[li];
            unsigned u0 = (unsigned)v.x, u1 = (unsigned)v.y, u2 = (unsigned)v.z, u3 = (unsigned)v.w;
            a0 = fmaf(bfbits2f(u0 << 16), m, a0);
            a1 = fmaf(bfbits2f(u0 & 0xffff0000u), m, a1);
            a2 = fmaf(bfbits2f(u1 << 16), m, a2);
            a3 = fmaf(bfbits2f(u1 & 0xffff0000u), m, a3);
            a4 = fmaf(bfbits2f(u2 << 16), m, a4);
            a5 = fmaf(bfbits2f(u2 & 0xffff0000u), m, a5);
            a6 = fmaf(bfbits2f(u3 << 16), m, a6);
            a7 = fmaf(bfbits2f(u3 & 0xffff0000u), m, a7);
        }
    }
    for (int i = 16; i < cnt; ++i) {  // rare tail (deg > 16)
        int s_ = bukAll[beg + i];
        int4 v = reinterpret_cast<const int4*>(h + (size_t)s_ * 128)[li];
        unsigned u0 = (unsigned)v.x, u1 = (unsigned)v.y, u2 = (unsigned)v.z, u3 = (unsigned)v.w;
        a0 += bfbits2f(u0 << 16);
        a1 += bfbits2f(u0 & 0xffff0000u);
        a2 += bfbits2f(u1 << 16);
        a3 += bfbits2f(u1 & 0xffff0000u);
        a4 += bfbits2f(u2 << 16);
        a5 += bfbits2f(u2 & 0xffff0000u);
        a6 += bfbits2f(u3 << 16);
        a7 += bfbits2f(u3 & 0xffff0000u);
    }

    float r = (cnt > 0) ? (1.0f / (float)cnt) : 0.0f;
    unsigned o0 = ((unsigned)(unsigned short)f2bf_bits(a1 * r) << 16) | (unsigned short)f2bf_bits(a0 * r);
    unsigned o1 = ((unsigned)(unsigned short)f2bf_bits(a3 * r) << 16) | (unsigned short)f2bf_bits(a2 * r);
    unsigned o2 = ((unsigned)(unsigned short)f2bf_bits(a5 * r) << 16) | (unsigned short)f2bf_bits(a4 * r);
    unsigned o3 = ((unsigned)(unsigned short)f2bf_bits(a7 * r) << 16) | (unsigned short)f2bf_bits(a6 * r);
    int4 ov;
    ov.x = (int)o0; ov.y = (int)o1; ov.z = (int)o2; ov.w = (int)o3;
    reinterpret_cast<int4*>(meanAll + (size_t)w * 128)[li] = ov;
}

// ---------------- fused SAGE update (MFMA), P and Q in one launch ----------------
// out[i,:] = act( hdst[i,:]@W0 + mean1[i,:]@W1 + mean2[i,:]@W2 + bias )
// B-fragments read straight from global (L2-resident W): no lW staging -> LDS 17.4KB, 3 blocks/CU
template <typename OT>
__global__ __launch_bounds__(256, 3)
void sage_all(const bf16* __restrict__ hQin, const bf16* __restrict__ hPin,
              const bf16* __restrict__ meanAll, const bf16* __restrict__ WtL,
              const float* __restrict__ bsumL,
              OT* __restrict__ outQ, OT* __restrict__ outP,
              int do_relu, int nblkP) {
    __shared__ short lA[64 * 136];  // stride 136 shorts (272B: 16B-aligned)
    const int tid = threadIdx.x;
    const int wave = tid >> 6, lane = tid & 63;
    const int i16 = lane & 15, quad = lane >> 4;

    const bool isP = (int)blockIdx.x < nblkP;
    const int blk = isP ? blockIdx.x : blockIdx.x - nblkP;
    const int row0 = blk * 64;
    const int nrows = isP ? NP_ : NQ_;
    const bf16* hdst = isP ? hPin : hQin;
    const bf16* m1 = meanAll + (isP ? (size_t)0 : (size_t)(2 * NP_)) * 128;
    const bf16* m2 = meanAll + (isP ? (size_t)NP_ : (size_t)(2 * NP_ + NQ_)) * 128;
    const bf16* Wt3 = WtL + (size_t)(isP ? 0 : 3) * 16384;
    const float* bs = bsumL + (isP ? 0 : 128);
    OT* out = isP ? outP : outQ;

    facc4 acc[4][2];
    for (int nt = 0; nt < 2; ++nt) {
        float bv = bs[wave * 32 + nt * 16 + i16];
        for (int mt = 0; mt < 4; ++mt) {
            facc4 a = {bv, bv, bv, bv};
            acc[mt][nt] = a;
        }
    }

    const bf16* Asrc[3] = {hdst, m1, m2};
#pragma unroll
    for (int s = 0; s < 3; ++s) {
        __syncthreads();
        // stage A_s (64 x 128 bf16)
        {
            const bf16* A = Asrc[s];
            for (int j = 0; j < 4; ++j) {
                int c = j * 256 + tid;
                int r = c >> 4, k = (c & 15) * 8;
                int grow = row0 + r;
                int4 v = {0, 0, 0, 0};
                if (grow < nrows)
                    v = reinterpret_cast<const int4*>(A)[((size_t)grow * 128 + k) >> 3];
                *reinterpret_cast<int4*>(&lA[r * 136 + k]) = v;
            }
        }
        __syncthreads();
        const bf16* Ws = Wt3 + (size_t)s * 16384;
#pragma unroll
        for (int k0 = 0; k0 < 128; k0 += 32) {
            bfrag8 a[4], b[2];
            for (int mt = 0; mt < 4; ++mt)
                a[mt] = *reinterpret_cast<const bfrag8*>(&lA[(mt * 16 + i16) * 136 + k0 + quad * 8]);
            for (int nt = 0; nt < 2; ++nt)
                b[nt] = *reinterpret_cast<const bfrag8*>(
                    Ws + (size_t)(wave * 32 + nt * 16 + i16) * 128 + k0 + quad * 8);
            for (int mt = 0; mt < 4; ++mt)
                for (int nt = 0; nt < 2; ++nt)
                    acc[mt][nt] = __builtin_amdgcn_mfma_f32_16x16x32_bf16(a[mt], b[nt], acc[mt][nt], 0, 0, 0);
        }
    }

    for (int mt = 0; mt < 4; ++mt) {
        for (int nt = 0; nt < 2; ++nt) {
            int n = wave * 32 + nt * 16 + i16;
            for (int r = 0; r < 4; ++r) {
                int m = mt * 16 + quad * 4 + r;
                int grow = row0 + m;
                if (grow < nrows) {
                    float v = acc[mt][nt][r];
                    if (do_relu) v = fmaxf(v, 0.0f);
                    store_val(out + (size_t)grow * 128 + n, v);
                }
            }
        }
    }
}

// ---------------- launch ----------------

extern "C" void kernel_launch(void* const* d_in, const int* in_sizes, int n_in,
                              void* d_out, int out_size, void* d_ws, size_t ws_size,
                              hipStream_t stream) {
    const float* xq     = (const float*)d_in[0];
    const float* xp     = (const float*)d_in[1];
    const float* Wself  = (const float*)d_in[2];
    const float* Wneigh = (const float*)d_in[3];
    const float* bias   = (const float*)d_in[4];
    const int* csrc  = (const int*)d_in[5];
    const int* cdst  = (const int*)d_in[6];
    const int* qsrc  = (const int*)d_in[7];
    const int* qdst  = (const int*)d_in[8];
    const int* rcsrc = (const int*)d_in[9];
    const int* rcdst = (const int*)d_in[10];
    const int* rqsrc = (const int*)d_in[11];
    const int* rqdst = (const int*)d_in[12];

    const int NDST = 2 * NP_ + 2 * NQ_;  // 600000 concatenated dst rows

    char* w = (char*)d_ws;
    bf16* xqb    = (bf16*)w;  w += (size_t)NQ_ * 128 * 2;
    bf16* xpb    = (bf16*)w;  w += (size_t)NP_ * 128 * 2;
    bf16* hQ1    = (bf16*)w;  w += (size_t)NQ_ * 128 * 2;
    bf16* hP1    = (bf16*)w;  w += (size_t)NP_ * 128 * 2;
    bf16* meanAll = (bf16*)w; w += (size_t)NDST * 128 * 2;
    bf16* Wt     = (bf16*)w;  w += (size_t)12 * 16384 * 2;
    float* bsum  = (float*)w; w += 512 * 4;
    int* degAll  = (int*)w;   w += (size_t)NDST * 4;
    int* offAll  = (int*)w;   w += (size_t)NDST * 4;
    int* rankAll = (int*)w;   w += (size_t)EDGE_TOTAL * 4;
    int* bukAll  = (int*)w;   w += (size_t)EDGE_TOTAL * 4;
    int* partials = (int*)w;  w += 1024 * 4;

    float* outQ = (float*)d_out;
    float* outP = outQ + (size_t)NQ_ * 128;

    // --- prep + CSR build ---
    hipMemsetAsync(degAll, 0, (size_t)NDST * 4, stream);
    fused_cast_deg<<<EDGE_BLOCKS, 256, 0, stream>>>(
        xq, xp, xqb, xpb, cdst, qdst, rcdst, rqdst, degAll, rankAll);
    int nparts = (NDST + 1023) / 1024;  // 586
    scan1<<<nparts, 256, 0, stream>>>(degAll, offAll, partials, NDST);
    scan2<<<1, 256, 0, stream>>>(partials, nparts);
    scan3<<<(NDST + 255) / 256, 256, 0, stream>>>(offAll, partials, NDST);
    fused_fill_prep<<<EDGE_BLOCKS + PREPW_BLOCKS + PREPB_BLOCKS, 256, 0, stream>>>(
        csrc, cdst, qsrc, qdst, rcsrc, rcdst, rqsrc, rqdst,
        offAll, rankAll, bukAll, Wself, Wneigh, Wt, bias, bsum);

    const int nblkP = (NP_ + 63) / 64;            // 3125
    const int nblkQ = (NQ_ + 63) / 64;            // 1563
    const int gather_blocks = NDST / 16;          // 37500 (exact: 16 rows per block)

    for (int l = 0; l < 2; ++l) {
        const bf16* hQin = l ? hQ1 : xqb;
        const bf16* hPin = l ? hP1 : xpb;
        const bf16* WtL = Wt + (size_t)l * 6 * 16384;
        const float* bL = bsum + l * 256;

        gather_all<<<gather_blocks, 256, 0, stream>>>(hQin, hPin, bukAll, offAll, degAll, meanAll);

        if (l == 0)
            sage_all<bf16><<<nblkP + nblkQ, 256, 0, stream>>>(hQin, hPin, meanAll, WtL, bL,
                                                              hQ1, hP1, 1, nblkP);
        else
            sage_all<float><<<nblkP + nblkQ, 256, 0, stream>>>(hQin, hPin, meanAll, WtL, bL,
                                                               outQ, outP, 0, nblkP);
    }
}